// Round 2
// baseline (21536.868 us; speedup 1.0000x reference)
//
#include <hip/hip_runtime.h>

// rnn_phy R3: single persistent megakernel. 720 launches -> 1 launch with 720
// device-scope global barriers (monotone counter + agent fences). Grid = 256 blocks
// x 512 threads, 87.6 KB static LDS -> exactly 1 block/CU, all blocks co-resident.
// Phase bodies are the R2 kernels (verified) looping over virtual block ids.
// k_gates K-chunked (2x96) and ff2 re-split to 8 K-slices of 256 so the LDS union
// fits and the barrier word fits inside the R2 workspace footprint.

#define Nn 512
#define Dd 130
#define DP 132
#define Hh 128
#define Ee 64
#define FFf 2048
#define TS 68
#define NB 256
#define NT 512

typedef float v4 __attribute__((ext_vector_type(4)));
typedef float v2 __attribute__((ext_vector_type(2)));

struct Args {
  const float *Tracks, *W_emb, *b_emb, *W_ih, *W_hh, *b_ih, *b_hh;
  const float *qkv_w, *qkv_b, *out_w, *out_b, *ff1_w, *ff1_b, *ff2_w, *ff2_b;
  const float *ln1_s, *ln1_b, *ln2_s, *ln2_b;
  const float *W_sp, *b_sp, *W_p1, *b_p1, *W_p2, *b_p2, *W_pl, *b_pl;
  float *X, *T, *Q, *Kb, *V, *O, *Sh, *C, *X1, *X2, *Y, *PART, *outp;
  unsigned *bar;
};

__device__ __forceinline__ float sigm(float x){ return 1.f/(1.f+__expf(-x)); }

// ---------------- Sh = X @ W_sp^T + b_sp (512x128, K=130), vgrid 16 ----------------
__device__ __forceinline__ void ph_proj(const Args& a, float* sm, int vb){
  int rg = vb & 7, cs = vb >> 3;
  int r0 = rg*64, c0 = cs*64;
  float* xs = sm; float* ws = sm + 13056;
  int tid = threadIdx.x, cg = tid & 15, ig = tid >> 4;
  __syncthreads();
  for (int idx=tid; idx<64*Dd; idx+=NT){ int i=idx/Dd, j=idx-i*Dd; xs[j*TS+i] = a.X[(r0+i)*DP+j]; }
  for (int idx=tid; idx<64*Dd; idx+=NT){ int c=idx/Dd, j=idx-c*Dd; ws[j*TS+c] = a.W_sp[(c0+c)*Dd+j]; }
  __syncthreads();
  float acc[2][4] = {};
  const float* xp = xs + 2*ig;
  const float* wp = ws + 4*cg;
  #pragma unroll 4
  for (int j=0;j<Dd;j++){
    v2 xv = *(const v2*)(xp + j*TS);
    v4 wv = *(const v4*)(wp + j*TS);
    #pragma unroll
    for (int aa=0;aa<2;aa++)
      #pragma unroll
      for (int bb=0;bb<4;bb++) acc[aa][bb] += xv[aa]*wv[bb];
  }
  #pragma unroll
  for (int aa=0;aa<2;aa++){
    int r = r0 + 2*ig + aa, c = c0 + 4*cg;
    v4 o;
    #pragma unroll
    for (int bb=0;bb<4;bb++) o[bb] = acc[aa][bb] + a.b_sp[c+bb];
    *(v4*)&a.Sh[r*Hh+c] = o;
  }
}

// ---------------- out = relu(in@W^T+b)+in (512x128, K=128), vgrid 16 ----------------
__device__ __forceinline__ void ph_mlp(const Args& a, float* sm, int vb,
                                       const float* inp, const float* W, const float* b, float* outp){
  int rg = vb & 7, cs = vb >> 3;
  int r0 = rg*64, c0 = cs*64;
  float* xs = sm; float* ws = sm + 13056;
  int tid = threadIdx.x, cg = tid & 15, ig = tid >> 4;
  __syncthreads();
  for (int idx=tid; idx<64*Hh; idx+=NT){ int i=idx>>7, j=idx&127; xs[j*TS+i] = inp[(r0+i)*Hh+j]; }
  for (int idx=tid; idx<64*Hh; idx+=NT){ int c=idx>>7, j=idx&127; ws[j*TS+c] = W[(c0+c)*Hh+j]; }
  __syncthreads();
  float acc[2][4] = {};
  const float* xp = xs + 2*ig;
  const float* wp = ws + 4*cg;
  #pragma unroll 4
  for (int j=0;j<Hh;j++){
    v2 xv = *(const v2*)(xp + j*TS);
    v4 wv = *(const v4*)(wp + j*TS);
    #pragma unroll
    for (int aa=0;aa<2;aa++)
      #pragma unroll
      for (int bb=0;bb<4;bb++) acc[aa][bb] += xv[aa]*wv[bb];
  }
  #pragma unroll
  for (int aa=0;aa<2;aa++){
    int r = r0 + 2*ig + aa, c = c0 + 4*cg;
    v4 ri = *(const v4*)&inp[r*Hh+c];
    v4 o;
    #pragma unroll
    for (int bb=0;bb<4;bb++) o[bb] = fmaxf(acc[aa][bb]+b[c+bb],0.f) + ri[bb];
    *(v4*)&outp[r*Hh+c] = o;
  }
}

// ---------------- pred head, vgrid 64 (8 rows/blk), first part gated to tid<256 ----------------
__device__ __forceinline__ void ph_pout(const Args& a, float* sm, int vb, int p){
  float* red = sm; // 16*17
  int r0 = vb*8;
  int tid = threadIdx.x;
  __syncthreads();
  if (tid < 256){
    int o = tid & 15, kq = tid >> 4;
    int ii = o>>1, jj = o&1, r = r0+ii;
    float s = 0.f;
    for (int v=kq*8; v<kq*8+8; v++) s += a.X2[r*Hh+v]*a.W_pl[jj*Hh+v];
    red[o*17+kq] = s;
  }
  __syncthreads();
  if (tid < 16){
    int oo=tid, i2=oo>>1, j=oo&1, rr=r0+i2;
    float av = a.b_pl[j];
    for (int k=0;k<16;k++) av += red[oo*17+k];
    float cf0, cf2;
    if (p==0){ cf0 = a.Tracks[(rr*20+19)*5+1+j]; cf2 = a.Tracks[(rr*20+19)*5+3+j]; }
    else     { cf0 = a.outp[rr*40+(p-1)*4+j];    cf2 = a.outp[rr*40+(p-1)*4+2+j]; }
    float vv = av*0.1f + cf2;
    float pn = av*0.005f + vv*0.1f + cf0;
    a.outp[rr*40+p*4+j]   = pn;
    a.outp[rr*40+p*4+2+j] = vv;
  }
}

// ---------------- emb + LSTM gates, vgrid 64 = 8rg x 8us, K chunked 2x96 ----------------
__device__ __forceinline__ void ph_gates(const Args& a, float* sm, int vb,
                                         int xin_mode, int tstep, int p, int sh_zero){
  int rg = vb & 7, us = vb >> 3;
  int r0 = rg*64, u0 = us*16;
  float* xs = sm;            // [96][68]
  float* ws = sm + 6528;     // [96][68]
  float* xin = sm + 13056;   // [256]
  int tid = threadIdx.x, cg = tid & 15, ig = tid >> 4;
  __syncthreads();
  for (int idx=tid; idx<64*4; idx+=NT){ int i=idx>>2, j=idx&3; int r=r0+i;
    xin[i*4+j] = (xin_mode==0) ? a.Tracks[(r*20+tstep)*5+1+j] : a.outp[r*40+p*4+j]; }
  float acc[2][4] = {};
  for (int ch=0; ch<2; ch++){
    __syncthreads();
    for (int idx=tid; idx<96*64; idx+=NT){ int kk=idx>>6, i=idx&63; int k=ch*96+kk;
      float v;
      if (k < Ee){
        v = a.b_emb[k];
        #pragma unroll
        for (int j=0;j<4;j++) v += xin[i*4+j]*a.W_emb[k*4+j];
      } else {
        v = sh_zero ? 0.f : a.Sh[(r0+i)*Hh + (k-Ee)];
      }
      xs[kk*TS+i] = v;
    }
    for (int idx=tid; idx<96*64; idx+=NT){ int kk=idx>>6, row=idx&63; int k=ch*96+kk;
      int u=row>>2, g=row&3; int wrow = g*Hh + u0 + u;
      ws[kk*TS+row] = (k<Ee) ? a.W_ih[wrow*Ee+k] : a.W_hh[wrow*Hh+(k-Ee)];
    }
    __syncthreads();
    const float* xp = xs + 2*ig;
    const float* wp = ws + 4*cg;
    #pragma unroll 4
    for (int jj=0;jj<96;jj++){
      v2 xv = *(const v2*)(xp + jj*TS);
      v4 wv = *(const v4*)(wp + jj*TS);
      #pragma unroll
      for (int aa=0;aa<2;aa++)
        #pragma unroll
        for (int bb=0;bb<4;bb++) acc[aa][bb] += xv[aa]*wv[bb];
    }
  }
  int u = u0 + cg;
  #pragma unroll
  for (int rr=0;rr<2;rr++){
    int r = r0 + 2*ig + rr;
    float gi = acc[rr][0] + a.b_ih[u]      + a.b_hh[u];
    float gf = acc[rr][1] + a.b_ih[Hh+u]   + a.b_hh[Hh+u];
    float gg = acc[rr][2] + a.b_ih[2*Hh+u] + a.b_hh[2*Hh+u];
    float go = acc[rr][3] + a.b_ih[3*Hh+u] + a.b_hh[3*Hh+u];
    float cp = sh_zero ? 0.f : a.C[r*Hh+u];
    float c2 = sigm(gf)*cp + sigm(gi)*tanhf(gg);
    a.C[r*Hh+u] = c2;
    a.X[r*DP+u] = sigm(go)*tanhf(c2);
  }
  if (us==0 && tid<128){ int i=tid>>1, jj=tid&1;
    a.X[(r0+i)*DP + Hh + jj] = xin[i*4+jj]; }
}

// ---------------- QKV: 512x390, K=130, vgrid 56 ----------------
__device__ __forceinline__ void ph_qkv(const Args& a, float* sm, int vb, int layer){
  int rg = vb & 7, cs = vb >> 3;
  int r0 = rg*64, c0 = cs*64;
  float* xs = sm; float* ws = sm + 13056;
  const float* qw = a.qkv_w + layer*390*Dd;
  const float* qb = a.qkv_b + layer*390;
  int tid = threadIdx.x, cg = tid & 15, ig = tid >> 4;
  __syncthreads();
  for (int idx=tid; idx<64*Dd; idx+=NT){ int i=idx/Dd, j=idx-i*Dd; xs[j*TS+i] = a.X[(r0+i)*DP+j]; }
  for (int idx=tid; idx<64*Dd; idx+=NT){ int c=idx/Dd, j=idx-c*Dd; int gc=c0+c;
    ws[j*TS+c] = (gc<390) ? qw[gc*Dd+j] : 0.f; }
  __syncthreads();
  float acc[2][4] = {};
  const float* xp = xs + 2*ig;
  const float* wp = ws + 4*cg;
  #pragma unroll 4
  for (int j=0;j<Dd;j++){
    v2 xv = *(const v2*)(xp + j*TS);
    v4 wv = *(const v4*)(wp + j*TS);
    #pragma unroll
    for (int aa=0;aa<2;aa++)
      #pragma unroll
      for (int bb=0;bb<4;bb++) acc[aa][bb] += xv[aa]*wv[bb];
  }
  #pragma unroll
  for (int aa=0;aa<2;aa++){
    int r = r0 + 2*ig + aa;
    #pragma unroll
    for (int bb=0;bb<4;bb++){
      int c = c0 + 4*cg + bb;
      if (c < 390){
        float v = acc[aa][bb] + qb[c];
        if (c < Dd)        a.Q [r*DP + c]        = v;
        else if (c < 2*Dd) a.Kb[r*DP + (c-Dd)]   = v;
        else               a.V [r*DP + (c-2*Dd)] = v;
      }
    }
  }
}

// ---------------- attention, vgrid 320 (16-row tile x head), 512 threads ----------------
__device__ __forceinline__ void ph_attn(const Args& a, float* sm, int vb){
  float* kv    = sm;          // [512*14] K;  then V^T [13][524]
  float* sc    = sm + 7168;   // [16*516]
  float* red   = sm + 15424;  // [16*33]
  float* rowm  = sm + 15952;  // [16]
  float* rowsi = sm + 15968;  // [16]
  float* red2  = sm + 15984;  // [416]
  int rg = vb & 31, head = vb >> 5;
  int r0 = rg*16, hc = head*13;
  int tid = threadIdx.x;
  const float scale = rsqrtf(13.f);
  __syncthreads();
  for (int idx=tid; idx<512*13; idx+=NT){ int m=idx/13, d=idx-13*m; kv[m*14+d]=a.Kb[m*DP+hc+d]; }
  __syncthreads();
  { int ii=tid>>5, mg=tid&31;
    float q[13];
    #pragma unroll
    for (int d=0;d<13;d++) q[d]=a.Q[(r0+ii)*DP+hc+d]*scale;
    for (int k=0;k<16;k++){ int m=mg+32*k;
      float s=0.f;
      #pragma unroll
      for (int d=0;d<13;d++) s += q[d]*kv[m*14+d];
      sc[ii*516+m]=s; } }
  __syncthreads();
  // V stage (transposed, reuses kv) + rowmax partials (disjoint LDS)
  for (int idx=tid; idx<512*13; idx+=NT){ int m=idx/13, d=idx-13*m; kv[d*524+m]=a.V[m*DP+hc+d]; }
  { int row=tid>>5, l=tid&31; float mx=-1e30f;
    for (int k=0;k<16;k++) mx=fmaxf(mx, sc[row*516+l+32*k]);
    red[row*33+l]=mx; }
  __syncthreads();
  if (tid<16){ float mx=-1e30f; for(int k=0;k<32;k++) mx=fmaxf(mx,red[tid*33+k]); rowm[tid]=mx; }
  __syncthreads();
  { int row=tid>>5, l=tid&31; float s=0.f; float mx=rowm[row];
    for (int k=0;k<16;k++){ int m=l+32*k; float e=__expf(sc[row*516+m]-mx); sc[row*516+m]=e; s+=e; }
    red[row*33+l]=s; }
  __syncthreads();
  if (tid<16){ float s=0.f; for(int k=0;k<32;k++) s+=red[tid*33+k]; rowsi[tid]=1.f/s; }
  __syncthreads();
  if (tid<416){ int pid=tid>>1, h=tid&1; int ii=pid/13, d=pid-13*ii;
    const float* sp = sc + ii*516 + h*256;
    const float* vp = kv + d*524 + h*256;
    float accv=0.f;
    #pragma unroll 4
    for (int mb=0;mb<64;mb++){
      v4 sv = *(const v4*)(sp + 4*mb);
      v4 vv = *(const v4*)(vp + 4*mb);
      accv += sv[0]*vv[0]+sv[1]*vv[1]+sv[2]*vv[2]+sv[3]*vv[3];
    }
    red2[pid*2+h]=accv; }
  __syncthreads();
  if (tid<208){ int ii=tid/13, d=tid-13*ii;
    a.O[(r0+ii)*DP+hc+d]=(red2[tid*2]+red2[tid*2+1])*rowsi[ii]; }
}

// ---------------- attn out-proj + residual, vgrid 24 ----------------
__device__ __forceinline__ void ph_oproj(const Args& a, float* sm, int vb, int layer){
  int rg = vb & 7, cs = vb >> 3;
  int r0 = rg*64, c0 = cs*64;
  float* xs = sm; float* ws = sm + 13056;
  const float* ow = a.out_w + layer*Dd*Dd;
  const float* ob = a.out_b + layer*Dd;
  int tid = threadIdx.x, cg = tid & 15, ig = tid >> 4;
  __syncthreads();
  for (int idx=tid; idx<64*Dd; idx+=NT){ int i=idx/Dd, j=idx-i*Dd; xs[j*TS+i]=a.O[(r0+i)*DP+j]; }
  for (int idx=tid; idx<64*Dd; idx+=NT){ int c=idx/Dd, j=idx-c*Dd; int gc=c0+c;
    ws[j*TS+c] = (gc<Dd) ? ow[gc*Dd+j] : 0.f; }
  __syncthreads();
  float acc[2][4] = {};
  const float* xp = xs + 2*ig;
  const float* wp = ws + 4*cg;
  #pragma unroll 4
  for (int j=0;j<Dd;j++){
    v2 xv = *(const v2*)(xp + j*TS);
    v4 wv = *(const v4*)(wp + j*TS);
    #pragma unroll
    for (int aa=0;aa<2;aa++)
      #pragma unroll
      for (int bb=0;bb<4;bb++) acc[aa][bb] += xv[aa]*wv[bb];
  }
  #pragma unroll
  for (int aa=0;aa<2;aa++){
    int r = r0 + 2*ig + aa;
    #pragma unroll
    for (int bb=0;bb<4;bb++){
      int c = c0 + 4*cg + bb;
      if (c < Dd) a.T[r*DP+c] = acc[aa][bb] + ob[c] + a.X[r*DP+c];
    }
  }
}

// ---------------- layernorm, vgrid 64; mode 1 sums 8 PART slices ----------------
__device__ __forceinline__ void ph_ln(const Args& a, float* sm, int vb,
                                      const float* s, const float* b, int mode_ff, int layer){
  float* row  = sm;          // 8*132
  float* red1 = sm + 1056;   // 8*33
  float* red2 = sm + 1320;   // 8*33
  float* mu   = sm + 1584;   // 8
  float* inv  = sm + 1592;   // 8
  int r0 = vb*8;
  int tid = threadIdx.x;
  __syncthreads();
  if (mode_ff==0){
    for (int idx=tid; idx<8*Dd; idx+=NT){ int ii=idx/Dd, c=idx-ii*Dd; row[ii*132+c]=a.T[(r0+ii)*DP+c]; }
  } else {
    const float* f2b = a.ff2_b + layer*Dd;
    for (int idx=tid; idx<8*Dd; idx+=NT){ int ii=idx/Dd, c=idx-ii*Dd;
      float sum = a.X[(r0+ii)*DP+c] + f2b[c];
      for (int ksl=0;ksl<8;ksl++) sum += a.PART[(ksl*Nn + r0+ii)*DP + c];
      row[ii*132+c]=sum; }
  }
  __syncthreads();
  if (tid<256){
    int i = tid>>5, l = tid&31;
    float s1=0.f, s2=0.f;
    for (int k=0;k<5;k++){ int c=l+32*k; if(c<Dd){ float v=row[i*132+c]; s1+=v; s2+=v*v; } }
    red1[i*33+l]=s1; red2[i*33+l]=s2;
  }
  __syncthreads();
  if (tid<8){ float s1=0.f,s2=0.f; for(int k=0;k<32;k++){ s1+=red1[tid*33+k]; s2+=red2[tid*33+k]; }
    float m=s1/130.f; mu[tid]=m; inv[tid]=rsqrtf(s2/130.f - m*m + 1e-5f); }
  __syncthreads();
  for (int idx=tid; idx<8*Dd; idx+=NT){ int ii=idx/Dd, c=idx-ii*Dd;
    a.X[(r0+ii)*DP+c] = (row[ii*132+c]-mu[ii])*inv[ii]*s[c] + b[c]; }
}

// ---------------- FF1: relu(X@W1^T+b1), 512x2048 K=130, vgrid 256 ----------------
__device__ __forceinline__ void ph_ff1(const Args& a, float* sm, int vb, int layer){
  int rg = vb & 7, cs = vb >> 3;
  int r0 = rg*64, c0 = cs*64;
  float* xs = sm; float* ws = sm + 13056;
  const float* w1 = a.ff1_w + layer*FFf*Dd;
  const float* b1 = a.ff1_b + layer*FFf;
  int tid = threadIdx.x, cg = tid & 15, ig = tid >> 4;
  __syncthreads();
  for (int idx=tid; idx<64*Dd; idx+=NT){ int i=idx/Dd, j=idx-i*Dd; xs[j*TS+i]=a.X[(r0+i)*DP+j]; }
  for (int idx=tid; idx<64*Dd; idx+=NT){ int c=idx/Dd, j=idx-c*Dd; ws[j*TS+c]=w1[(c0+c)*Dd+j]; }
  __syncthreads();
  float acc[2][4] = {};
  const float* xp = xs + 2*ig;
  const float* wp = ws + 4*cg;
  #pragma unroll 4
  for (int j=0;j<Dd;j++){
    v2 xv = *(const v2*)(xp + j*TS);
    v4 wv = *(const v4*)(wp + j*TS);
    #pragma unroll
    for (int aa=0;aa<2;aa++)
      #pragma unroll
      for (int bb=0;bb<4;bb++) acc[aa][bb] += xv[aa]*wv[bb];
  }
  #pragma unroll
  for (int aa=0;aa<2;aa++){
    int r = r0 + 2*ig + aa, c = c0 + 4*cg;
    v4 o;
    #pragma unroll
    for (int bb=0;bb<4;bb++) o[bb] = fmaxf(acc[aa][bb]+b1[c+bb],0.f);
    *(v4*)&a.Y[r*FFf+c] = o;
  }
}

// ---------------- FF2 partials: 8 K-slices of 256 (2 staged chunks), vgrid 192 ----------------
__device__ __forceinline__ void ph_ff2(const Args& a, float* sm, int vb, int layer){
  int rg = vb & 7; int t = vb >> 3; int ks = t/3; int cs = t - ks*3;
  int r0 = rg*64, c0 = cs*64, k0 = ks*256;
  float* xs = sm; float* ws = sm + 13056;
  const float* w2 = a.ff2_w + layer*Dd*FFf;
  int tid = threadIdx.x, cg = tid & 15, ig = tid >> 4;
  float acc[2][4] = {};
  for (int ch=0; ch<2; ch++){
    __syncthreads();
    int kb = k0 + ch*128;
    for (int idx=tid; idx<64*128; idx+=NT){ int i=idx>>7, j=idx&127; xs[j*TS+i]=a.Y[(r0+i)*FFf+kb+j]; }
    for (int idx=tid; idx<64*128; idx+=NT){ int c=idx>>7, j=idx&127; int gc=c0+c;
      ws[j*TS+c] = (gc<Dd) ? w2[gc*FFf+kb+j] : 0.f; }
    __syncthreads();
    const float* xp = xs + 2*ig;
    const float* wp = ws + 4*cg;
    #pragma unroll 4
    for (int j=0;j<128;j++){
      v2 xv = *(const v2*)(xp + j*TS);
      v4 wv = *(const v4*)(wp + j*TS);
      #pragma unroll
      for (int aa=0;aa<2;aa++)
        #pragma unroll
        for (int bb=0;bb<4;bb++) acc[aa][bb] += xv[aa]*wv[bb];
    }
  }
  #pragma unroll
  for (int aa=0;aa<2;aa++){
    int r = r0 + 2*ig + aa;
    #pragma unroll
    for (int bb=0;bb<4;bb++){
      int c = c0 + 4*cg + bb;
      if (c < Dd) a.PART[(ks*Nn + r)*DP + c] = acc[aa][bb];
    }
  }
}

#define FORVB(G) for (int vb = (int)blockIdx.x; vb < (G); vb += NB)

__global__ __launch_bounds__(NT, 1) void mega(Args a){
  __shared__ float sm[21896];   // 87.6 KB -> 1 block/CU
  unsigned tgt = 0;
  unsigned* bar = a.bar;

  auto GSYNC = [&](){
    __syncthreads();
    if (threadIdx.x == 0){
      tgt += NB;
      __threadfence();
      __hip_atomic_fetch_add(bar, 1u, __ATOMIC_RELAXED, __HIP_MEMORY_SCOPE_AGENT);
      while (__hip_atomic_load(bar, __ATOMIC_RELAXED, __HIP_MEMORY_SCOPE_AGENT) < tgt){
        __builtin_amdgcn_s_sleep(1);
      }
      __threadfence();
    }
    __syncthreads();
  };

  auto enc = [&](){
    for (int l=0;l<3;l++){
      FORVB(56)  ph_qkv  (a, sm, vb, l);                                   GSYNC();
      FORVB(320) ph_attn (a, sm, vb);                                      GSYNC();
      FORVB(24)  ph_oproj(a, sm, vb, l);                                   GSYNC();
      FORVB(64)  ph_ln   (a, sm, vb, a.ln1_s+l*Dd, a.ln1_b+l*Dd, 0, l);    GSYNC();
      FORVB(256) ph_ff1  (a, sm, vb, l);                                   GSYNC();
      FORVB(192) ph_ff2  (a, sm, vb, l);                                   GSYNC();
      FORVB(64)  ph_ln   (a, sm, vb, a.ln2_s+l*Dd, a.ln2_b+l*Dd, 1, l);    GSYNC();
    }
  };

  // init step
  FORVB(64) ph_gates(a, sm, vb, 0, 0, 0, 1);  GSYNC();
  enc();
  // 20 history steps
  for (int t=0;t<20;t++){
    FORVB(16) ph_proj (a, sm, vb);            GSYNC();
    FORVB(64) ph_gates(a, sm, vb, 0, t, 0, 0); GSYNC();
    enc();
  }
  // 10 prediction steps
  for (int p=0;p<10;p++){
    FORVB(16) ph_proj(a, sm, vb);                                  GSYNC();
    FORVB(16) ph_mlp (a, sm, vb, a.Sh, a.W_p1, a.b_p1, a.X1);      GSYNC();
    FORVB(16) ph_mlp (a, sm, vb, a.X1, a.W_p2, a.b_p2, a.X2);      GSYNC();
    FORVB(64) ph_pout(a, sm, vb, p);                               GSYNC();
    if (p < 9){
      FORVB(64) ph_gates(a, sm, vb, 1, 0, p, 0);                   GSYNC();
      enc();
    }
  }
}

extern "C" void kernel_launch(void* const* d_in, const int* in_sizes, int n_in,
                              void* d_out, int out_size, void* d_ws, size_t ws_size,
                              hipStream_t stream) {
  (void)in_sizes; (void)n_in; (void)out_size; (void)ws_size;
  Args A;
  const float* const* in = (const float* const*)d_in;
  A.Tracks=in[0]; A.W_emb=in[1]; A.b_emb=in[2]; A.W_ih=in[3]; A.W_hh=in[4]; A.b_ih=in[5]; A.b_hh=in[6];
  A.qkv_w=in[7]; A.qkv_b=in[8]; A.out_w=in[9]; A.out_b=in[10];
  A.ff1_w=in[11]; A.ff1_b=in[12]; A.ff2_w=in[13]; A.ff2_b=in[14];
  A.ln1_s=in[15]; A.ln1_b=in[16]; A.ln2_s=in[17]; A.ln2_b=in[18];
  A.W_sp=in[19]; A.b_sp=in[20]; A.W_p1=in[21]; A.b_p1=in[22]; A.W_p2=in[23]; A.b_p2=in[24];
  A.W_pl=in[25]; A.b_pl=in[26];
  float* ws = (float*)d_ws;
  A.X   = ws;
  A.T   = ws + 67584;
  A.Q   = ws + 135168;
  A.Kb  = ws + 202752;
  A.V   = ws + 270336;
  A.O   = ws + 337920;
  A.Sh  = ws + 405504;
  A.C   = ws + 471040;
  A.X1  = ws + 536576;
  A.X2  = ws + 602112;
  A.Y   = ws + 667648;
  A.PART= ws + 1716224;                 // 8 * 512 * 132 = 540672 floats
  A.bar = (unsigned*)(ws + 2256896);    // right after PART, inside R2 footprint
  A.outp = (float*)d_out;

  hipMemsetAsync((void*)A.bar, 0, 64, stream);
  mega<<<dim3(NB), dim3(NT), 0, stream>>>(A);
}

// Round 3
// 19575.690 us; speedup vs baseline: 1.1002x; 1.1002x over previous
//
#include <hip/hip_runtime.h>

// rnn_phy R4: megakernel with HIERARCHICAL global barrier.
// R3's flat barrier (256 atomics + 256 spinners on ONE line) cost ~24us/barrier
// (VALUBusy 5.9%, huge replay variance = contention nondeterminism).
// R4: 2-level barrier: 16 groups x 16 blocks, every counter/epoch flag on its own
// 128B line, <=15 contenders per line, s_sleep(4) polls. Phase bodies unchanged
// from R3 (verified absmax 0.0).

#define Nn 512
#define Dd 130
#define DP 132
#define Hh 128
#define Ee 64
#define FFf 2048
#define TS 68
#define NB 256
#define NT 512

typedef float v4 __attribute__((ext_vector_type(4)));
typedef float v2 __attribute__((ext_vector_type(2)));

struct Args {
  const float *Tracks, *W_emb, *b_emb, *W_ih, *W_hh, *b_ih, *b_hh;
  const float *qkv_w, *qkv_b, *out_w, *out_b, *ff1_w, *ff1_b, *ff2_w, *ff2_b;
  const float *ln1_s, *ln1_b, *ln2_s, *ln2_b;
  const float *W_sp, *b_sp, *W_p1, *b_p1, *W_p2, *b_p2, *W_pl, *b_pl;
  float *X, *T, *Q, *Kb, *V, *O, *Sh, *C, *X1, *X2, *Y, *PART, *outp;
  unsigned *bar;
};

__device__ __forceinline__ float sigm(float x){ return 1.f/(1.f+__expf(-x)); }

// ---------------- Sh = X @ W_sp^T + b_sp (512x128, K=130), vgrid 16 ----------------
__device__ __forceinline__ void ph_proj(const Args& a, float* sm, int vb){
  int rg = vb & 7, cs = vb >> 3;
  int r0 = rg*64, c0 = cs*64;
  float* xs = sm; float* ws = sm + 13056;
  int tid = threadIdx.x, cg = tid & 15, ig = tid >> 4;
  __syncthreads();
  for (int idx=tid; idx<64*Dd; idx+=NT){ int i=idx/Dd, j=idx-i*Dd; xs[j*TS+i] = a.X[(r0+i)*DP+j]; }
  for (int idx=tid; idx<64*Dd; idx+=NT){ int c=idx/Dd, j=idx-c*Dd; ws[j*TS+c] = a.W_sp[(c0+c)*Dd+j]; }
  __syncthreads();
  float acc[2][4] = {};
  const float* xp = xs + 2*ig;
  const float* wp = ws + 4*cg;
  #pragma unroll 4
  for (int j=0;j<Dd;j++){
    v2 xv = *(const v2*)(xp + j*TS);
    v4 wv = *(const v4*)(wp + j*TS);
    #pragma unroll
    for (int aa=0;aa<2;aa++)
      #pragma unroll
      for (int bb=0;bb<4;bb++) acc[aa][bb] += xv[aa]*wv[bb];
  }
  #pragma unroll
  for (int aa=0;aa<2;aa++){
    int r = r0 + 2*ig + aa, c = c0 + 4*cg;
    v4 o;
    #pragma unroll
    for (int bb=0;bb<4;bb++) o[bb] = acc[aa][bb] + a.b_sp[c+bb];
    *(v4*)&a.Sh[r*Hh+c] = o;
  }
}

// ---------------- out = relu(in@W^T+b)+in (512x128, K=128), vgrid 16 ----------------
__device__ __forceinline__ void ph_mlp(const Args& a, float* sm, int vb,
                                       const float* inp, const float* W, const float* b, float* outp){
  int rg = vb & 7, cs = vb >> 3;
  int r0 = rg*64, c0 = cs*64;
  float* xs = sm; float* ws = sm + 13056;
  int tid = threadIdx.x, cg = tid & 15, ig = tid >> 4;
  __syncthreads();
  for (int idx=tid; idx<64*Hh; idx+=NT){ int i=idx>>7, j=idx&127; xs[j*TS+i] = inp[(r0+i)*Hh+j]; }
  for (int idx=tid; idx<64*Hh; idx+=NT){ int c=idx>>7, j=idx&127; ws[j*TS+c] = W[(c0+c)*Hh+j]; }
  __syncthreads();
  float acc[2][4] = {};
  const float* xp = xs + 2*ig;
  const float* wp = ws + 4*cg;
  #pragma unroll 4
  for (int j=0;j<Hh;j++){
    v2 xv = *(const v2*)(xp + j*TS);
    v4 wv = *(const v4*)(wp + j*TS);
    #pragma unroll
    for (int aa=0;aa<2;aa++)
      #pragma unroll
      for (int bb=0;bb<4;bb++) acc[aa][bb] += xv[aa]*wv[bb];
  }
  #pragma unroll
  for (int aa=0;aa<2;aa++){
    int r = r0 + 2*ig + aa, c = c0 + 4*cg;
    v4 ri = *(const v4*)&inp[r*Hh+c];
    v4 o;
    #pragma unroll
    for (int bb=0;bb<4;bb++) o[bb] = fmaxf(acc[aa][bb]+b[c+bb],0.f) + ri[bb];
    *(v4*)&outp[r*Hh+c] = o;
  }
}

// ---------------- pred head, vgrid 64 (8 rows/blk) ----------------
__device__ __forceinline__ void ph_pout(const Args& a, float* sm, int vb, int p){
  float* red = sm; // 16*17
  int r0 = vb*8;
  int tid = threadIdx.x;
  __syncthreads();
  if (tid < 256){
    int o = tid & 15, kq = tid >> 4;
    int ii = o>>1, jj = o&1, r = r0+ii;
    float s = 0.f;
    for (int v=kq*8; v<kq*8+8; v++) s += a.X2[r*Hh+v]*a.W_pl[jj*Hh+v];
    red[o*17+kq] = s;
  }
  __syncthreads();
  if (tid < 16){
    int oo=tid, i2=oo>>1, j=oo&1, rr=r0+i2;
    float av = a.b_pl[j];
    for (int k=0;k<16;k++) av += red[oo*17+k];
    float cf0, cf2;
    if (p==0){ cf0 = a.Tracks[(rr*20+19)*5+1+j]; cf2 = a.Tracks[(rr*20+19)*5+3+j]; }
    else     { cf0 = a.outp[rr*40+(p-1)*4+j];    cf2 = a.outp[rr*40+(p-1)*4+2+j]; }
    float vv = av*0.1f + cf2;
    float pn = av*0.005f + vv*0.1f + cf0;
    a.outp[rr*40+p*4+j]   = pn;
    a.outp[rr*40+p*4+2+j] = vv;
  }
}

// ---------------- emb + LSTM gates, vgrid 64 = 8rg x 8us, K chunked 2x96 ----------------
__device__ __forceinline__ void ph_gates(const Args& a, float* sm, int vb,
                                         int xin_mode, int tstep, int p, int sh_zero){
  int rg = vb & 7, us = vb >> 3;
  int r0 = rg*64, u0 = us*16;
  float* xs = sm;            // [96][68]
  float* ws = sm + 6528;     // [96][68]
  float* xin = sm + 13056;   // [256]
  int tid = threadIdx.x, cg = tid & 15, ig = tid >> 4;
  __syncthreads();
  for (int idx=tid; idx<64*4; idx+=NT){ int i=idx>>2, j=idx&3; int r=r0+i;
    xin[i*4+j] = (xin_mode==0) ? a.Tracks[(r*20+tstep)*5+1+j] : a.outp[r*40+p*4+j]; }
  float acc[2][4] = {};
  for (int ch=0; ch<2; ch++){
    __syncthreads();
    for (int idx=tid; idx<96*64; idx+=NT){ int kk=idx>>6, i=idx&63; int k=ch*96+kk;
      float v;
      if (k < Ee){
        v = a.b_emb[k];
        #pragma unroll
        for (int j=0;j<4;j++) v += xin[i*4+j]*a.W_emb[k*4+j];
      } else {
        v = sh_zero ? 0.f : a.Sh[(r0+i)*Hh + (k-Ee)];
      }
      xs[kk*TS+i] = v;
    }
    for (int idx=tid; idx<96*64; idx+=NT){ int kk=idx>>6, row=idx&63; int k=ch*96+kk;
      int u=row>>2, g=row&3; int wrow = g*Hh + u0 + u;
      ws[kk*TS+row] = (k<Ee) ? a.W_ih[wrow*Ee+k] : a.W_hh[wrow*Hh+(k-Ee)];
    }
    __syncthreads();
    const float* xp = xs + 2*ig;
    const float* wp = ws + 4*cg;
    #pragma unroll 4
    for (int jj=0;jj<96;jj++){
      v2 xv = *(const v2*)(xp + jj*TS);
      v4 wv = *(const v4*)(wp + jj*TS);
      #pragma unroll
      for (int aa=0;aa<2;aa++)
        #pragma unroll
        for (int bb=0;bb<4;bb++) acc[aa][bb] += xv[aa]*wv[bb];
    }
  }
  int u = u0 + cg;
  #pragma unroll
  for (int rr=0;rr<2;rr++){
    int r = r0 + 2*ig + rr;
    float gi = acc[rr][0] + a.b_ih[u]      + a.b_hh[u];
    float gf = acc[rr][1] + a.b_ih[Hh+u]   + a.b_hh[Hh+u];
    float gg = acc[rr][2] + a.b_ih[2*Hh+u] + a.b_hh[2*Hh+u];
    float go = acc[rr][3] + a.b_ih[3*Hh+u] + a.b_hh[3*Hh+u];
    float cp = sh_zero ? 0.f : a.C[r*Hh+u];
    float c2 = sigm(gf)*cp + sigm(gi)*tanhf(gg);
    a.C[r*Hh+u] = c2;
    a.X[r*DP+u] = sigm(go)*tanhf(c2);
  }
  if (us==0 && tid<128){ int i=tid>>1, jj=tid&1;
    a.X[(r0+i)*DP + Hh + jj] = xin[i*4+jj]; }
}

// ---------------- QKV: 512x390, K=130, vgrid 56 ----------------
__device__ __forceinline__ void ph_qkv(const Args& a, float* sm, int vb, int layer){
  int rg = vb & 7, cs = vb >> 3;
  int r0 = rg*64, c0 = cs*64;
  float* xs = sm; float* ws = sm + 13056;
  const float* qw = a.qkv_w + layer*390*Dd;
  const float* qb = a.qkv_b + layer*390;
  int tid = threadIdx.x, cg = tid & 15, ig = tid >> 4;
  __syncthreads();
  for (int idx=tid; idx<64*Dd; idx+=NT){ int i=idx/Dd, j=idx-i*Dd; xs[j*TS+i] = a.X[(r0+i)*DP+j]; }
  for (int idx=tid; idx<64*Dd; idx+=NT){ int c=idx/Dd, j=idx-c*Dd; int gc=c0+c;
    ws[j*TS+c] = (gc<390) ? qw[gc*Dd+j] : 0.f; }
  __syncthreads();
  float acc[2][4] = {};
  const float* xp = xs + 2*ig;
  const float* wp = ws + 4*cg;
  #pragma unroll 4
  for (int j=0;j<Dd;j++){
    v2 xv = *(const v2*)(xp + j*TS);
    v4 wv = *(const v4*)(wp + j*TS);
    #pragma unroll
    for (int aa=0;aa<2;aa++)
      #pragma unroll
      for (int bb=0;bb<4;bb++) acc[aa][bb] += xv[aa]*wv[bb];
  }
  #pragma unroll
  for (int aa=0;aa<2;aa++){
    int r = r0 + 2*ig + aa;
    #pragma unroll
    for (int bb=0;bb<4;bb++){
      int c = c0 + 4*cg + bb;
      if (c < 390){
        float v = acc[aa][bb] + qb[c];
        if (c < Dd)        a.Q [r*DP + c]        = v;
        else if (c < 2*Dd) a.Kb[r*DP + (c-Dd)]   = v;
        else               a.V [r*DP + (c-2*Dd)] = v;
      }
    }
  }
}

// ---------------- attention, vgrid 320 (16-row tile x head), 512 threads ----------------
__device__ __forceinline__ void ph_attn(const Args& a, float* sm, int vb){
  float* kv    = sm;          // [512*14] K;  then V^T [13][524]
  float* sc    = sm + 7168;   // [16*516]
  float* red   = sm + 15424;  // [16*33]
  float* rowm  = sm + 15952;  // [16]
  float* rowsi = sm + 15968;  // [16]
  float* red2  = sm + 15984;  // [416]
  int rg = vb & 31, head = vb >> 5;
  int r0 = rg*16, hc = head*13;
  int tid = threadIdx.x;
  const float scale = rsqrtf(13.f);
  __syncthreads();
  for (int idx=tid; idx<512*13; idx+=NT){ int m=idx/13, d=idx-13*m; kv[m*14+d]=a.Kb[m*DP+hc+d]; }
  __syncthreads();
  { int ii=tid>>5, mg=tid&31;
    float q[13];
    #pragma unroll
    for (int d=0;d<13;d++) q[d]=a.Q[(r0+ii)*DP+hc+d]*scale;
    for (int k=0;k<16;k++){ int m=mg+32*k;
      float s=0.f;
      #pragma unroll
      for (int d=0;d<13;d++) s += q[d]*kv[m*14+d];
      sc[ii*516+m]=s; } }
  __syncthreads();
  for (int idx=tid; idx<512*13; idx+=NT){ int m=idx/13, d=idx-13*m; kv[d*524+m]=a.V[m*DP+hc+d]; }
  { int row=tid>>5, l=tid&31; float mx=-1e30f;
    for (int k=0;k<16;k++) mx=fmaxf(mx, sc[row*516+l+32*k]);
    red[row*33+l]=mx; }
  __syncthreads();
  if (tid<16){ float mx=-1e30f; for(int k=0;k<32;k++) mx=fmaxf(mx,red[tid*33+k]); rowm[tid]=mx; }
  __syncthreads();
  { int row=tid>>5, l=tid&31; float s=0.f; float mx=rowm[row];
    for (int k=0;k<16;k++){ int m=l+32*k; float e=__expf(sc[row*516+m]-mx); sc[row*516+m]=e; s+=e; }
    red[row*33+l]=s; }
  __syncthreads();
  if (tid<16){ float s=0.f; for(int k=0;k<32;k++) s+=red[tid*33+k]; rowsi[tid]=1.f/s; }
  __syncthreads();
  if (tid<416){ int pid=tid>>1, h=tid&1; int ii=pid/13, d=pid-13*ii;
    const float* sp = sc + ii*516 + h*256;
    const float* vp = kv + d*524 + h*256;
    float accv=0.f;
    #pragma unroll 4
    for (int mb=0;mb<64;mb++){
      v4 sv = *(const v4*)(sp + 4*mb);
      v4 vv = *(const v4*)(vp + 4*mb);
      accv += sv[0]*vv[0]+sv[1]*vv[1]+sv[2]*vv[2]+sv[3]*vv[3];
    }
    red2[pid*2+h]=accv; }
  __syncthreads();
  if (tid<208){ int ii=tid/13, d=tid-13*ii;
    a.O[(r0+ii)*DP+hc+d]=(red2[tid*2]+red2[tid*2+1])*rowsi[ii]; }
}

// ---------------- attn out-proj + residual, vgrid 24 ----------------
__device__ __forceinline__ void ph_oproj(const Args& a, float* sm, int vb, int layer){
  int rg = vb & 7, cs = vb >> 3;
  int r0 = rg*64, c0 = cs*64;
  float* xs = sm; float* ws = sm + 13056;
  const float* ow = a.out_w + layer*Dd*Dd;
  const float* ob = a.out_b + layer*Dd;
  int tid = threadIdx.x, cg = tid & 15, ig = tid >> 4;
  __syncthreads();
  for (int idx=tid; idx<64*Dd; idx+=NT){ int i=idx/Dd, j=idx-i*Dd; xs[j*TS+i]=a.O[(r0+i)*DP+j]; }
  for (int idx=tid; idx<64*Dd; idx+=NT){ int c=idx/Dd, j=idx-c*Dd; int gc=c0+c;
    ws[j*TS+c] = (gc<Dd) ? ow[gc*Dd+j] : 0.f; }
  __syncthreads();
  float acc[2][4] = {};
  const float* xp = xs + 2*ig;
  const float* wp = ws + 4*cg;
  #pragma unroll 4
  for (int j=0;j<Dd;j++){
    v2 xv = *(const v2*)(xp + j*TS);
    v4 wv = *(const v4*)(wp + j*TS);
    #pragma unroll
    for (int aa=0;aa<2;aa++)
      #pragma unroll
      for (int bb=0;bb<4;bb++) acc[aa][bb] += xv[aa]*wv[bb];
  }
  #pragma unroll
  for (int aa=0;aa<2;aa++){
    int r = r0 + 2*ig + aa;
    #pragma unroll
    for (int bb=0;bb<4;bb++){
      int c = c0 + 4*cg + bb;
      if (c < Dd) a.T[r*DP+c] = acc[aa][bb] + ob[c] + a.X[r*DP+c];
    }
  }
}

// ---------------- layernorm, vgrid 64; mode 1 sums 8 PART slices ----------------
__device__ __forceinline__ void ph_ln(const Args& a, float* sm, int vb,
                                      const float* s, const float* b, int mode_ff, int layer){
  float* row  = sm;          // 8*132
  float* red1 = sm + 1056;   // 8*33
  float* red2 = sm + 1320;   // 8*33
  float* mu   = sm + 1584;   // 8
  float* inv  = sm + 1592;   // 8
  int r0 = vb*8;
  int tid = threadIdx.x;
  __syncthreads();
  if (mode_ff==0){
    for (int idx=tid; idx<8*Dd; idx+=NT){ int ii=idx/Dd, c=idx-ii*Dd; row[ii*132+c]=a.T[(r0+ii)*DP+c]; }
  } else {
    const float* f2b = a.ff2_b + layer*Dd;
    for (int idx=tid; idx<8*Dd; idx+=NT){ int ii=idx/Dd, c=idx-ii*Dd;
      float sum = a.X[(r0+ii)*DP+c] + f2b[c];
      for (int ksl=0;ksl<8;ksl++) sum += a.PART[(ksl*Nn + r0+ii)*DP + c];
      row[ii*132+c]=sum; }
  }
  __syncthreads();
  if (tid<256){
    int i = tid>>5, l = tid&31;
    float s1=0.f, s2=0.f;
    for (int k=0;k<5;k++){ int c=l+32*k; if(c<Dd){ float v=row[i*132+c]; s1+=v; s2+=v*v; } }
    red1[i*33+l]=s1; red2[i*33+l]=s2;
  }
  __syncthreads();
  if (tid<8){ float s1=0.f,s2=0.f; for(int k=0;k<32;k++){ s1+=red1[tid*33+k]; s2+=red2[tid*33+k]; }
    float m=s1/130.f; mu[tid]=m; inv[tid]=rsqrtf(s2/130.f - m*m + 1e-5f); }
  __syncthreads();
  for (int idx=tid; idx<8*Dd; idx+=NT){ int ii=idx/Dd, c=idx-ii*Dd;
    a.X[(r0+ii)*DP+c] = (row[ii*132+c]-mu[ii])*inv[ii]*s[c] + b[c]; }
}

// ---------------- FF1: relu(X@W1^T+b1), 512x2048 K=130, vgrid 256 ----------------
__device__ __forceinline__ void ph_ff1(const Args& a, float* sm, int vb, int layer){
  int rg = vb & 7, cs = vb >> 3;
  int r0 = rg*64, c0 = cs*64;
  float* xs = sm; float* ws = sm + 13056;
  const float* w1 = a.ff1_w + layer*FFf*Dd;
  const float* b1 = a.ff1_b + layer*FFf;
  int tid = threadIdx.x, cg = tid & 15, ig = tid >> 4;
  __syncthreads();
  for (int idx=tid; idx<64*Dd; idx+=NT){ int i=idx/Dd, j=idx-i*Dd; xs[j*TS+i]=a.X[(r0+i)*DP+j]; }
  for (int idx=tid; idx<64*Dd; idx+=NT){ int c=idx/Dd, j=idx-c*Dd; ws[j*TS+c]=w1[(c0+c)*Dd+j]; }
  __syncthreads();
  float acc[2][4] = {};
  const float* xp = xs + 2*ig;
  const float* wp = ws + 4*cg;
  #pragma unroll 4
  for (int j=0;j<Dd;j++){
    v2 xv = *(const v2*)(xp + j*TS);
    v4 wv = *(const v4*)(wp + j*TS);
    #pragma unroll
    for (int aa=0;aa<2;aa++)
      #pragma unroll
      for (int bb=0;bb<4;bb++) acc[aa][bb] += xv[aa]*wv[bb];
  }
  #pragma unroll
  for (int aa=0;aa<2;aa++){
    int r = r0 + 2*ig + aa, c = c0 + 4*cg;
    v4 o;
    #pragma unroll
    for (int bb=0;bb<4;bb++) o[bb] = fmaxf(acc[aa][bb]+b1[c+bb],0.f);
    *(v4*)&a.Y[r*FFf+c] = o;
  }
}

// ---------------- FF2 partials: 8 K-slices of 256 (2 staged chunks), vgrid 192 ----------------
__device__ __forceinline__ void ph_ff2(const Args& a, float* sm, int vb, int layer){
  int rg = vb & 7; int t = vb >> 3; int ks = t/3; int cs = t - ks*3;
  int r0 = rg*64, c0 = cs*64, k0 = ks*256;
  float* xs = sm; float* ws = sm + 13056;
  const float* w2 = a.ff2_w + layer*Dd*FFf;
  int tid = threadIdx.x, cg = tid & 15, ig = tid >> 4;
  float acc[2][4] = {};
  for (int ch=0; ch<2; ch++){
    __syncthreads();
    int kb = k0 + ch*128;
    for (int idx=tid; idx<64*128; idx+=NT){ int i=idx>>7, j=idx&127; xs[j*TS+i]=a.Y[(r0+i)*FFf+kb+j]; }
    for (int idx=tid; idx<64*128; idx+=NT){ int c=idx>>7, j=idx&127; int gc=c0+c;
      ws[j*TS+c] = (gc<Dd) ? w2[gc*FFf+kb+j] : 0.f; }
    __syncthreads();
    const float* xp = xs + 2*ig;
    const float* wp = ws + 4*cg;
    #pragma unroll 4
    for (int j=0;j<128;j++){
      v2 xv = *(const v2*)(xp + j*TS);
      v4 wv = *(const v4*)(wp + j*TS);
      #pragma unroll
      for (int aa=0;aa<2;aa++)
        #pragma unroll
        for (int bb=0;bb<4;bb++) acc[aa][bb] += xv[aa]*wv[bb];
    }
  }
  #pragma unroll
  for (int aa=0;aa<2;aa++){
    int r = r0 + 2*ig + aa;
    #pragma unroll
    for (int bb=0;bb<4;bb++){
      int c = c0 + 4*cg + bb;
      if (c < Dd) a.PART[(ks*Nn + r)*DP + c] = acc[aa][bb];
    }
  }
}

#define FORVB(G) for (int vb = (int)blockIdx.x; vb < (G); vb += NB)

__global__ __launch_bounds__(NT, 1) void mega(Args a){
  __shared__ float sm[21896];   // 87.6 KB -> 1 block/CU
  unsigned e = 0;
  unsigned* bar = a.bar;
  // layout (each slot on its own 128B line = 32 uints):
  //   grp_cnt[g] = bar + 32*g          (g = 0..15)
  //   root_cnt   = bar + 32*16
  //   root_rel   = bar + 32*17
  //   grp_rel[g] = bar + 32*(18+g)
  const int bid = (int)blockIdx.x, grp = bid >> 4, lid = bid & 15;
  unsigned* gc  = bar + 32*grp;
  unsigned* rc  = bar + 32*16;
  unsigned* rel = bar + 32*17;
  unsigned* gr  = bar + 32*(18+grp);

  auto GSYNC = [&](){
    __syncthreads();
    if (threadIdx.x == 0){
      e += 1;
      __threadfence();
      if (lid){
        __hip_atomic_fetch_add(gc, 1u, __ATOMIC_RELAXED, __HIP_MEMORY_SCOPE_AGENT);
        while (__hip_atomic_load(gr, __ATOMIC_RELAXED, __HIP_MEMORY_SCOPE_AGENT) < e)
          __builtin_amdgcn_s_sleep(4);
      } else if (bid){
        while (__hip_atomic_load(gc, __ATOMIC_RELAXED, __HIP_MEMORY_SCOPE_AGENT) < 15u*e)
          __builtin_amdgcn_s_sleep(4);
        __hip_atomic_fetch_add(rc, 1u, __ATOMIC_RELAXED, __HIP_MEMORY_SCOPE_AGENT);
        while (__hip_atomic_load(rel, __ATOMIC_RELAXED, __HIP_MEMORY_SCOPE_AGENT) < e)
          __builtin_amdgcn_s_sleep(4);
        __hip_atomic_store(gr, e, __ATOMIC_RELAXED, __HIP_MEMORY_SCOPE_AGENT);
      } else {
        while (__hip_atomic_load(gc, __ATOMIC_RELAXED, __HIP_MEMORY_SCOPE_AGENT) < 15u*e)
          __builtin_amdgcn_s_sleep(4);
        while (__hip_atomic_load(rc, __ATOMIC_RELAXED, __HIP_MEMORY_SCOPE_AGENT) < 15u*e)
          __builtin_amdgcn_s_sleep(4);
        __hip_atomic_store(rel, e, __ATOMIC_RELAXED, __HIP_MEMORY_SCOPE_AGENT);
        __hip_atomic_store(gr, e, __ATOMIC_RELAXED, __HIP_MEMORY_SCOPE_AGENT);
      }
      __threadfence();
    }
    __syncthreads();
  };

  auto enc = [&](){
    for (int l=0;l<3;l++){
      FORVB(56)  ph_qkv  (a, sm, vb, l);                                   GSYNC();
      FORVB(320) ph_attn (a, sm, vb);                                      GSYNC();
      FORVB(24)  ph_oproj(a, sm, vb, l);                                   GSYNC();
      FORVB(64)  ph_ln   (a, sm, vb, a.ln1_s+l*Dd, a.ln1_b+l*Dd, 0, l);    GSYNC();
      FORVB(256) ph_ff1  (a, sm, vb, l);                                   GSYNC();
      FORVB(192) ph_ff2  (a, sm, vb, l);                                   GSYNC();
      FORVB(64)  ph_ln   (a, sm, vb, a.ln2_s+l*Dd, a.ln2_b+l*Dd, 1, l);    GSYNC();
    }
  };

  // init step
  FORVB(64) ph_gates(a, sm, vb, 0, 0, 0, 1);  GSYNC();
  enc();
  // 20 history steps
  for (int t=0;t<20;t++){
    FORVB(16) ph_proj (a, sm, vb);            GSYNC();
    FORVB(64) ph_gates(a, sm, vb, 0, t, 0, 0); GSYNC();
    enc();
  }
  // 10 prediction steps
  for (int p=0;p<10;p++){
    FORVB(16) ph_proj(a, sm, vb);                                  GSYNC();
    FORVB(16) ph_mlp (a, sm, vb, a.Sh, a.W_p1, a.b_p1, a.X1);      GSYNC();
    FORVB(16) ph_mlp (a, sm, vb, a.X1, a.W_p2, a.b_p2, a.X2);      GSYNC();
    FORVB(64) ph_pout(a, sm, vb, p);                               GSYNC();
    if (p < 9){
      FORVB(64) ph_gates(a, sm, vb, 1, 0, p, 0);                   GSYNC();
      enc();
    }
  }
}

extern "C" void kernel_launch(void* const* d_in, const int* in_sizes, int n_in,
                              void* d_out, int out_size, void* d_ws, size_t ws_size,
                              hipStream_t stream) {
  (void)in_sizes; (void)n_in; (void)out_size; (void)ws_size;
  Args A;
  const float* const* in = (const float* const*)d_in;
  A.Tracks=in[0]; A.W_emb=in[1]; A.b_emb=in[2]; A.W_ih=in[3]; A.W_hh=in[4]; A.b_ih=in[5]; A.b_hh=in[6];
  A.qkv_w=in[7]; A.qkv_b=in[8]; A.out_w=in[9]; A.out_b=in[10];
  A.ff1_w=in[11]; A.ff1_b=in[12]; A.ff2_w=in[13]; A.ff2_b=in[14];
  A.ln1_s=in[15]; A.ln1_b=in[16]; A.ln2_s=in[17]; A.ln2_b=in[18];
  A.W_sp=in[19]; A.b_sp=in[20]; A.W_p1=in[21]; A.b_p1=in[22]; A.W_p2=in[23]; A.b_p2=in[24];
  A.W_pl=in[25]; A.b_pl=in[26];
  float* ws = (float*)d_ws;
  A.X   = ws;
  A.T   = ws + 67584;
  A.Q   = ws + 135168;
  A.Kb  = ws + 202752;
  A.V   = ws + 270336;
  A.O   = ws + 337920;
  A.Sh  = ws + 405504;
  A.C   = ws + 471040;
  A.X1  = ws + 536576;
  A.X2  = ws + 602112;
  A.Y   = ws + 667648;
  A.PART= ws + 1716224;                 // 8 * 512 * 132 = 540672 floats
  A.bar = (unsigned*)(ws + 2256896);    // 34 slots x 128B = 4352B
  A.outp = (float*)d_out;

  hipMemsetAsync((void*)A.bar, 0, 8192, stream);
  mega<<<dim3(NB), dim3(NT), 0, stream>>>(A);
}

// Round 4
// 11107.962 us; speedup vs baseline: 1.9389x; 1.7623x over previous
//
#include <hip/hip_runtime.h>

// rnn_phy R5: multi-kernel (megakernel abandoned: agent-fence = L2 wb/inv = ~25us/barrier).
// vs R2 (9.06ms): (1) all big GEMM cores converted to 4x4 k-major register tiles
// (v4 x-rows + v4 w-cols per j, tid<256 compute) -> ~2x less LDS-port pressure,
// bit-identical per-output j-order; (2) k_bnd fuses boundary glue (ln2+proj[+mlp,mlp,pout])
// at grid 64, cutting 720 -> 660 launches and the pred tail 6->2 kernels.

#define Nn 512
#define Dd 130
#define DP 132
#define Hh 128
#define Ee 64
#define FFf 2048
#define TS 68

typedef float v4 __attribute__((ext_vector_type(4)));
typedef float v2 __attribute__((ext_vector_type(2)));

struct Args {
  const float *Tracks, *W_emb, *b_emb, *W_ih, *W_hh, *b_ih, *b_hh;
  const float *qkv_w, *qkv_b, *out_w, *out_b, *ff1_w, *ff1_b, *ff2_w, *ff2_b;
  const float *ln1_s, *ln1_b, *ln2_s, *ln2_b;
  const float *W_sp, *b_sp, *W_p1, *b_p1, *W_p2, *b_p2, *W_pl, *b_pl;
  float *X, *T, *Q, *Kb, *V, *O, *Sh, *C, *Y, *PART, *outp;
};

__device__ __forceinline__ float sigm(float x){ return 1.f/(1.f+__expf(-x)); }

// 4x4 fat-tile core: xs/ws k-major stride TS. tid<256: cg=tid&15 (4 cols), ig=(tid>>4)&15 (4 rows).
#define FATCORE(KK) \
  { const float* xp = xs + 4*ig; \
    const float* wp = ws + 4*cg; \
    _Pragma("unroll 2") \
    for (int j=0;j<(KK);j++){ \
      v4 xv = *(const v4*)(xp + j*TS); \
      v4 wv = *(const v4*)(wp + j*TS); \
      _Pragma("unroll") \
      for (int aa=0;aa<4;aa++) \
        _Pragma("unroll") \
        for (int bb=0;bb<4;bb++) acc[aa][bb] += xv[aa]*wv[bb]; \
    } }

// ---------------- emb + LSTM gates. grid 64 = 8rg x 8us, K chunked 2x96 ----------------
__global__ __launch_bounds__(512) void k_gates(Args a, int xin_mode, int tstep, int p, int sh_zero){
  int rg = blockIdx.x & 7, us = blockIdx.x >> 3;
  int r0 = rg*64, u0 = us*16;
  __shared__ alignas(16) float xs[96*TS];
  __shared__ alignas(16) float ws[96*TS];
  __shared__ float xin[64*4];
  int tid = threadIdx.x, cg = tid & 15, ig = (tid>>4) & 15;
  for (int idx=tid; idx<64*4; idx+=512){ int i=idx>>2, j=idx&3; int r=r0+i;
    xin[i*4+j] = (xin_mode==0) ? a.Tracks[(r*20+tstep)*5+1+j] : a.outp[r*40+p*4+j]; }
  float acc[4][4] = {};
  for (int ch=0; ch<2; ch++){
    __syncthreads();
    for (int idx=tid; idx<96*64; idx+=512){ int kk=idx>>6, i=idx&63; int k=ch*96+kk;
      float v;
      if (k < Ee){
        v = a.b_emb[k];
        #pragma unroll
        for (int j=0;j<4;j++) v += xin[i*4+j]*a.W_emb[k*4+j];
      } else {
        v = sh_zero ? 0.f : a.Sh[(r0+i)*Hh + (k-Ee)];
      }
      xs[kk*TS+i] = v;
    }
    for (int idx=tid; idx<96*64; idx+=512){ int kk=idx>>6, row=idx&63; int k=ch*96+kk;
      int u=row>>2, g=row&3; int wrow = g*Hh + u0 + u;
      ws[kk*TS+row] = (k<Ee) ? a.W_ih[wrow*Ee+k] : a.W_hh[wrow*Hh+(k-Ee)];
    }
    __syncthreads();
    if (tid < 256) FATCORE(96)
  }
  if (tid < 256){
    int u = u0 + cg;
    #pragma unroll
    for (int aa=0;aa<4;aa++){
      int r = r0 + 4*ig + aa;
      float gi = acc[aa][0] + a.b_ih[u]      + a.b_hh[u];
      float gf = acc[aa][1] + a.b_ih[Hh+u]   + a.b_hh[Hh+u];
      float gg = acc[aa][2] + a.b_ih[2*Hh+u] + a.b_hh[2*Hh+u];
      float go = acc[aa][3] + a.b_ih[3*Hh+u] + a.b_hh[3*Hh+u];
      float cp = sh_zero ? 0.f : a.C[r*Hh+u];
      float c2 = sigm(gf)*cp + sigm(gi)*tanhf(gg);
      a.C[r*Hh+u] = c2;
      a.X[r*DP+u] = sigm(go)*tanhf(c2);
    }
  }
  if (us==0 && tid<128){ int i=tid>>1, jj=tid&1;
    a.X[(r0+i)*DP + Hh + jj] = xin[i*4+jj]; }
}

// ---------------- QKV: 512x390, K=130. grid 56 = 8rg x 7cs ----------------
__global__ __launch_bounds__(512) void k_qkv(Args a, int layer){
  int rg = blockIdx.x & 7, cs = blockIdx.x >> 3;
  int r0 = rg*64, c0 = cs*64;
  __shared__ alignas(16) float xs[132*TS];
  __shared__ alignas(16) float ws[132*TS];
  const float* qw = a.qkv_w + layer*390*Dd;
  const float* qb = a.qkv_b + layer*390;
  int tid = threadIdx.x, cg = tid & 15, ig = (tid>>4) & 15;
  for (int idx=tid; idx<64*Dd; idx+=512){ int i=idx/Dd, j=idx-i*Dd; xs[j*TS+i] = a.X[(r0+i)*DP+j]; }
  for (int idx=tid; idx<64*Dd; idx+=512){ int c=idx/Dd, j=idx-c*Dd; int gc=c0+c;
    ws[j*TS+c] = (gc<390) ? qw[gc*Dd+j] : 0.f; }
  __syncthreads();
  float acc[4][4] = {};
  if (tid < 256){
    FATCORE(Dd)
    #pragma unroll
    for (int aa=0;aa<4;aa++){
      int r = r0 + 4*ig + aa;
      #pragma unroll
      for (int bb=0;bb<4;bb++){
        int c = c0 + 4*cg + bb;
        if (c < 390){
          float v = acc[aa][bb] + qb[c];
          if (c < Dd)        a.Q [r*DP + c]        = v;
          else if (c < 2*Dd) a.Kb[r*DP + (c-Dd)]   = v;
          else               a.V [r*DP + (c-2*Dd)] = v;
        }
      }
    }
  }
}

// ---------------- attention: one block per (16-row tile, head). grid 320, 256 thr ----------------
__global__ __launch_bounds__(256) void k_attn(Args a){
  int rg = blockIdx.x & 31, head = blockIdx.x >> 5;
  int r0 = rg*16, hc = head*13;
  __shared__ alignas(16) float kv[512*14];   // phase 1: K [m][14]; phase 2: V^T [13][524]
  __shared__ alignas(16) float sc[16*516];
  __shared__ float red[16*17];
  __shared__ float rowm[16], rowsi[16];
  int tid = threadIdx.x;
  const float scale = rsqrtf(13.f);
  for (int idx=tid; idx<512*13; idx+=256){ int m=idx/13, d=idx-13*m; kv[m*14+d]=a.Kb[m*DP+hc+d]; }
  __syncthreads();
  { int ii=tid>>4, mg=tid&15;
    float q[13];
    #pragma unroll
    for (int d=0;d<13;d++) q[d]=a.Q[(r0+ii)*DP+hc+d]*scale;
    for (int k=0;k<32;k++){ int m=mg+16*k;
      float s=0.f;
      #pragma unroll
      for (int d=0;d<13;d++) s += q[d]*kv[m*14+d];
      sc[ii*516+m]=s; } }
  __syncthreads();
  for (int idx=tid; idx<512*13; idx+=256){ int m=idx/13, d=idx-13*m; kv[d*524+m]=a.V[m*DP+hc+d]; }
  { int row=tid>>4, l=tid&15; float mx=-1e30f;
    for (int k=0;k<32;k++) mx=fmaxf(mx, sc[row*516+l+16*k]);
    red[row*17+l]=mx; }
  __syncthreads();
  if (tid<16){ float mx=-1e30f; for(int k=0;k<16;k++) mx=fmaxf(mx,red[tid*17+k]); rowm[tid]=mx; }
  __syncthreads();
  { int row=tid>>4, l=tid&15; float s=0.f; float mx=rowm[row];
    for (int k=0;k<32;k++){ int m=l+16*k; float e=__expf(sc[row*516+m]-mx); sc[row*516+m]=e; s+=e; }
    red[row*17+l]=s; }
  __syncthreads();
  if (tid<16){ float s=0.f; for(int k=0;k<16;k++) s+=red[tid*17+k]; rowsi[tid]=1.f/s; }
  __syncthreads();
  if (tid<208){ int ii=tid/13, d=tid-13*ii;
    float accv=0.f;
    const float* sp = sc + ii*516;
    const float* vp = kv + d*524;
    #pragma unroll 4
    for (int mb=0;mb<128;mb++){
      v4 sv = *(const v4*)(sp + 4*mb);
      v4 vv = *(const v4*)(vp + 4*mb);
      accv += sv[0]*vv[0]+sv[1]*vv[1]+sv[2]*vv[2]+sv[3]*vv[3];
    }
    a.O[(r0+ii)*DP+hc+d]=accv*rowsi[ii]; }
}

// ---------------- attn out-proj + residual: T = O@ow^T + ob + X. grid 24 = 8rg x 3cs ----------------
__global__ __launch_bounds__(512) void k_oproj(Args a, int layer){
  int rg = blockIdx.x & 7, cs = blockIdx.x >> 3;
  int r0 = rg*64, c0 = cs*64;
  __shared__ alignas(16) float xs[132*TS];
  __shared__ alignas(16) float ws[132*TS];
  const float* ow = a.out_w + layer*Dd*Dd;
  const float* ob = a.out_b + layer*Dd;
  int tid = threadIdx.x, cg = tid & 15, ig = (tid>>4) & 15;
  for (int idx=tid; idx<64*Dd; idx+=512){ int i=idx/Dd, j=idx-i*Dd; xs[j*TS+i]=a.O[(r0+i)*DP+j]; }
  for (int idx=tid; idx<64*Dd; idx+=512){ int c=idx/Dd, j=idx-c*Dd; int gc=c0+c;
    ws[j*TS+c] = (gc<Dd) ? ow[gc*Dd+j] : 0.f; }
  __syncthreads();
  float acc[4][4] = {};
  if (tid < 256){
    FATCORE(Dd)
    #pragma unroll
    for (int aa=0;aa<4;aa++){
      int r = r0 + 4*ig + aa;
      #pragma unroll
      for (int bb=0;bb<4;bb++){
        int c = c0 + 4*cg + bb;
        if (c < Dd) a.T[r*DP+c] = acc[aa][bb] + ob[c] + a.X[r*DP+c];
      }
    }
  }
}

// ---------------- layernorm (mode 0: from T; mode 1: X + ff2_b + sum of 8 PART slices) -----------
__global__ __launch_bounds__(256) void k_ln(Args a, const float* s, const float* b, int mode_ff, int layer){
  int r0 = blockIdx.x*8;
  __shared__ float row[8*132];
  __shared__ float red1[8*33], red2[8*33];
  __shared__ float mu[8], inv[8];
  int tid = threadIdx.x, i = tid>>5, l = tid&31;
  if (mode_ff==0){
    for (int idx=tid; idx<8*Dd; idx+=256){ int ii=idx/Dd, c=idx-ii*Dd; row[ii*132+c]=a.T[(r0+ii)*DP+c]; }
  } else {
    const float* f2b = a.ff2_b + layer*Dd;
    for (int idx=tid; idx<8*Dd; idx+=256){ int ii=idx/Dd, c=idx-ii*Dd;
      float sum = a.X[(r0+ii)*DP+c] + f2b[c];
      for (int ksl=0;ksl<8;ksl++) sum += a.PART[(ksl*Nn + r0+ii)*DP + c];
      row[ii*132+c]=sum; }
  }
  __syncthreads();
  { float s1=0.f, s2=0.f;
    for (int k=0;k<5;k++){ int c=l+32*k; if(c<Dd){ float v=row[i*132+c]; s1+=v; s2+=v*v; } }
    red1[i*33+l]=s1; red2[i*33+l]=s2; }
  __syncthreads();
  if (tid<8){ float s1=0.f,s2=0.f; for(int k=0;k<32;k++){ s1+=red1[tid*33+k]; s2+=red2[tid*33+k]; }
    float m=s1/130.f; mu[tid]=m; inv[tid]=rsqrtf(s2/130.f - m*m + 1e-5f); }
  __syncthreads();
  for (int idx=tid; idx<8*Dd; idx+=256){ int ii=idx/Dd, c=idx-ii*Dd;
    a.X[(r0+ii)*DP+c] = (row[ii*132+c]-mu[ii])*inv[ii]*s[c] + b[c]; }
}

// ---------------- FF1: Y = relu(X@W1^T + b1), 512x2048 K=130. grid 256 = 8rg x 32cs ----------------
__global__ __launch_bounds__(512) void k_ff1(Args a, int layer){
  int rg = blockIdx.x & 7, cs = blockIdx.x >> 3;
  int r0 = rg*64, c0 = cs*64;
  __shared__ alignas(16) float xs[132*TS];
  __shared__ alignas(16) float ws[132*TS];
  const float* w1 = a.ff1_w + layer*FFf*Dd;
  const float* b1 = a.ff1_b + layer*FFf;
  int tid = threadIdx.x, cg = tid & 15, ig = (tid>>4) & 15;
  for (int idx=tid; idx<64*Dd; idx+=512){ int i=idx/Dd, j=idx-i*Dd; xs[j*TS+i]=a.X[(r0+i)*DP+j]; }
  for (int idx=tid; idx<64*Dd; idx+=512){ int c=idx/Dd, j=idx-c*Dd; ws[j*TS+c]=w1[(c0+c)*Dd+j]; }
  __syncthreads();
  float acc[4][4] = {};
  if (tid < 256){
    FATCORE(Dd)
    #pragma unroll
    for (int aa=0;aa<4;aa++){
      int r = r0 + 4*ig + aa, c = c0 + 4*cg;
      v4 o;
      #pragma unroll
      for (int bb=0;bb<4;bb++) o[bb] = fmaxf(acc[aa][bb]+b1[c+bb],0.f);
      *(v4*)&a.Y[r*FFf+c] = o;
    }
  }
}

// ---------------- FF2 partials: 8 K-slices of 256 (2 staged chunks). grid 192 = 8rg x 3cs x 8ks ----
__global__ __launch_bounds__(512) void k_ff2(Args a, int layer){
  int bidx = blockIdx.x;
  int rg = bidx & 7; int t = bidx >> 3; int ks = t/3; int cs = t - ks*3;
  int r0 = rg*64, c0 = cs*64, k0 = ks*256;
  __shared__ alignas(16) float xs[128*TS];
  __shared__ alignas(16) float ws[128*TS];
  const float* w2 = a.ff2_w + layer*Dd*FFf;
  int tid = threadIdx.x, cg = tid & 15, ig = (tid>>4) & 15;
  float acc[4][4] = {};
  for (int ch=0; ch<2; ch++){
    __syncthreads();
    int kb = k0 + ch*128;
    for (int idx=tid; idx<64*128; idx+=512){ int i=idx>>7, j=idx&127; xs[j*TS+i]=a.Y[(r0+i)*FFf+kb+j]; }
    for (int idx=tid; idx<64*128; idx+=512){ int c=idx>>7, j=idx&127; int gc=c0+c;
      ws[j*TS+c] = (gc<Dd) ? w2[gc*FFf+kb+j] : 0.f; }
    __syncthreads();
    if (tid < 256) FATCORE(128)
  }
  if (tid < 256){
    #pragma unroll
    for (int aa=0;aa<4;aa++){
      int r = r0 + 4*ig + aa;
      #pragma unroll
      for (int bb=0;bb<4;bb++){
        int c = c0 + 4*cg + bb;
        if (c < Dd) a.PART[(ks*Nn + r)*DP + c] = acc[aa][bb];
      }
    }
  }
}

// ---------------- boundary fusion: ln2(layer2) + proj [+ mlp1 + mlp2 + pout]. grid 64, 8 rows -----
__global__ __launch_bounds__(512) void k_bnd(Args a, int do_mlp, int p){
  int r0 = blockIdx.x*8;
  __shared__ float row8[8*132];
  __shared__ float sh8[8*132];
  __shared__ alignas(16) float xsk[132*12];
  __shared__ alignas(16) float ws[132*TS];
  __shared__ float red1[8*33], red2[8*33], mu[8], inv[8];
  __shared__ float pred_[16*17];
  int tid = threadIdx.x;
  const float* f2b = a.ff2_b + 2*Dd;
  const float* lns = a.ln2_s + 2*Dd;
  const float* lnb = a.ln2_b + 2*Dd;
  // ---- ln2 (mode1, 8 PART slices), layer 2 ----
  for (int idx=tid; idx<8*Dd; idx+=512){ int ii=idx/Dd, c=idx-ii*Dd;
    float sum = a.X[(r0+ii)*DP+c] + f2b[c];
    for (int ksl=0;ksl<8;ksl++) sum += a.PART[(ksl*Nn + r0+ii)*DP + c];
    row8[ii*132+c]=sum; }
  __syncthreads();
  if (tid<256){ int i=tid>>5, l=tid&31;
    float s1=0.f, s2=0.f;
    for (int k=0;k<5;k++){ int c=l+32*k; if(c<Dd){ float v=row8[i*132+c]; s1+=v; s2+=v*v; } }
    red1[i*33+l]=s1; red2[i*33+l]=s2; }
  __syncthreads();
  if (tid<8){ float s1=0.f,s2=0.f; for(int k=0;k<32;k++){ s1+=red1[tid*33+k]; s2+=red2[tid*33+k]; }
    float m=s1/130.f; mu[tid]=m; inv[tid]=rsqrtf(s2/130.f - m*m + 1e-5f); }
  __syncthreads();
  for (int idx=tid; idx<8*Dd; idx+=512){ int ii=idx/Dd, c=idx-ii*Dd;
    float v = (row8[ii*132+c]-mu[ii])*inv[ii]*lns[c] + lnb[c];
    a.X[(r0+ii)*DP+c] = v; row8[ii*132+c] = v; }
  __syncthreads();
  // ---- proj: Sh = X@W_sp^T + b_sp (8 x 128, K=130) ----
  for (int idx=tid; idx<132*8; idx+=512){ int j=idx>>3, r=idx&7;
    xsk[j*12+r] = (j<Dd) ? row8[r*132+j] : 0.f; }
  for (int cc=0; cc<2; cc++){
    __syncthreads();
    for (int idx=tid; idx<64*Dd; idx+=512){ int cl=idx/Dd, j=idx-cl*Dd;
      ws[j*TS+cl] = a.W_sp[(cc*64+cl)*Dd+j]; }
    __syncthreads();
    if (tid<64){
      int ip = tid>>4, cg = tid&15;
      float acc[2][4] = {};
      for (int j=0;j<Dd;j++){
        v2 xv = *(const v2*)(xsk + j*12 + 2*ip);
        v4 wv = *(const v4*)(ws + j*TS + 4*cg);
        #pragma unroll
        for (int aa=0;aa<2;aa++)
          #pragma unroll
          for (int bb=0;bb<4;bb++) acc[aa][bb] += xv[aa]*wv[bb];
      }
      #pragma unroll
      for (int aa=0;aa<2;aa++)
        #pragma unroll
        for (int bb=0;bb<4;bb++){
          int r = 2*ip+aa, c = cc*64 + 4*cg + bb;
          float v = acc[aa][bb] + a.b_sp[c];
          sh8[r*132+c] = v;
          a.Sh[(r0+r)*Hh+c] = v;
        }
    }
  }
  if (!do_mlp) return;
  // ---- mlp1 / mlp2: out = relu(in@W^T+b)+in (8 x 128, K=128) ----
  for (int m=0;m<2;m++){
    const float* W  = m ? a.W_p2 : a.W_p1;
    const float* bi = m ? a.b_p2 : a.b_p1;
    float* src = m ? row8 : sh8;   // m0: Sh -> X1(row8); m1: X1 -> X2(sh8)
    float* dst = m ? sh8  : row8;
    __syncthreads();
    for (int idx=tid; idx<128*8; idx+=512){ int j=idx>>3, r=idx&7; xsk[j*12+r]=src[r*132+j]; }
    for (int cc=0; cc<2; cc++){
      __syncthreads();
      for (int idx=tid; idx<64*Hh; idx+=512){ int cl=idx>>7, j=idx&127;
        ws[j*TS+cl] = W[(cc*64+cl)*Hh+j]; }
      __syncthreads();
      if (tid<64){
        int ip = tid>>4, cg = tid&15;
        float acc[2][4] = {};
        for (int j=0;j<Hh;j++){
          v2 xv = *(const v2*)(xsk + j*12 + 2*ip);
          v4 wv = *(const v4*)(ws + j*TS + 4*cg);
          #pragma unroll
          for (int aa=0;aa<2;aa++)
            #pragma unroll
            for (int bb=0;bb<4;bb++) acc[aa][bb] += xv[aa]*wv[bb];
        }
        #pragma unroll
        for (int aa=0;aa<2;aa++)
          #pragma unroll
          for (int bb=0;bb<4;bb++){
            int r = 2*ip+aa, c = cc*64 + 4*cg + bb;
            dst[r*132+c] = fmaxf(acc[aa][bb]+bi[c],0.f) + src[r*132+c];
          }
      }
    }
  }
  __syncthreads();
  // ---- pout: a = X2@W_pl^T + b_pl; integrate; write outp (X2 in sh8) ----
  if (tid < 256){
    int o = tid & 15, kq = tid >> 4;
    int ii = o>>1, jj = o&1;
    float s = 0.f;
    for (int v=kq*8; v<kq*8+8; v++) s += sh8[ii*132+v]*a.W_pl[jj*Hh+v];
    pred_[o*17+kq] = s;
  }
  __syncthreads();
  if (tid < 16){
    int oo=tid, i2=oo>>1, j=oo&1, rr=r0+i2;
    float av = a.b_pl[j];
    for (int k=0;k<16;k++) av += pred_[oo*17+k];
    float cf0, cf2;
    if (p==0){ cf0 = a.Tracks[(rr*20+19)*5+1+j]; cf2 = a.Tracks[(rr*20+19)*5+3+j]; }
    else     { cf0 = a.outp[rr*40+(p-1)*4+j];    cf2 = a.outp[rr*40+(p-1)*4+2+j]; }
    float vv = av*0.1f + cf2;
    float pn = av*0.005f + vv*0.1f + cf0;
    a.outp[rr*40+p*4+j]   = pn;
    a.outp[rr*40+p*4+2+j] = vv;
  }
}

extern "C" void kernel_launch(void* const* d_in, const int* in_sizes, int n_in,
                              void* d_out, int out_size, void* d_ws, size_t ws_size,
                              hipStream_t stream) {
  (void)in_sizes; (void)n_in; (void)out_size; (void)ws_size;
  Args A;
  const float* const* in = (const float* const*)d_in;
  A.Tracks=in[0]; A.W_emb=in[1]; A.b_emb=in[2]; A.W_ih=in[3]; A.W_hh=in[4]; A.b_ih=in[5]; A.b_hh=in[6];
  A.qkv_w=in[7]; A.qkv_b=in[8]; A.out_w=in[9]; A.out_b=in[10];
  A.ff1_w=in[11]; A.ff1_b=in[12]; A.ff2_w=in[13]; A.ff2_b=in[14];
  A.ln1_s=in[15]; A.ln1_b=in[16]; A.ln2_s=in[17]; A.ln2_b=in[18];
  A.W_sp=in[19]; A.b_sp=in[20]; A.W_p1=in[21]; A.b_p1=in[22]; A.W_p2=in[23]; A.b_p2=in[24];
  A.W_pl=in[25]; A.b_pl=in[26];
  float* ws = (float*)d_ws;
  A.X   = ws;
  A.T   = ws + 67584;
  A.Q   = ws + 135168;
  A.Kb  = ws + 202752;
  A.V   = ws + 270336;
  A.O   = ws + 337920;
  A.Sh  = ws + 405504;
  A.C   = ws + 471040;
  A.Y   = ws + 667648;
  A.PART= ws + 1716224;   // 8 * 512 * 132
  A.outp = (float*)d_out;

  dim3 B5(512), B2(256);
  auto enc = [&](){
    for (int l=0;l<3;l++){
      k_qkv  <<<dim3(56),  B5, 0, stream>>>(A, l);
      k_attn <<<dim3(320), B2, 0, stream>>>(A);
      k_oproj<<<dim3(24),  B5, 0, stream>>>(A, l);
      k_ln   <<<dim3(64),  B2, 0, stream>>>(A, A.ln1_s+l*Dd, A.ln1_b+l*Dd, 0, l);
      k_ff1  <<<dim3(256), B5, 0, stream>>>(A, l);
      k_ff2  <<<dim3(192), B5, 0, stream>>>(A, l);
      if (l < 2)
        k_ln <<<dim3(64),  B2, 0, stream>>>(A, A.ln2_s+l*Dd, A.ln2_b+l*Dd, 1, l);
    }
  };

  // init step: lstm(emb(Tracks[:,0,1:]), 0, 0) -> encoder
  k_gates<<<dim3(64), B5, 0, stream>>>(A, 0, 0, 0, 1);
  for (int pass=0; pass<30; ++pass){
    enc();
    if (pass < 20){
      k_bnd  <<<dim3(64), B5, 0, stream>>>(A, 0, 0);
      k_gates<<<dim3(64), B5, 0, stream>>>(A, 0, pass, 0, 0);
    } else if (pass < 29){
      int p = pass - 20;
      k_bnd  <<<dim3(64), B5, 0, stream>>>(A, 1, p);
      k_gates<<<dim3(64), B5, 0, stream>>>(A, 1, 0, p, 0);
    } else {
      k_bnd  <<<dim3(64), B5, 0, stream>>>(A, 1, 9);
    }
  }
}

// Round 5
// 9417.905 us; speedup vs baseline: 2.2868x; 1.1795x over previous
//
#include <hip/hip_runtime.h>

// rnn_phy R6 = R2 (proven 9.06ms) + three zero-parallelism-loss fusions:
//  - ln1 folded into k_ff1 prologue (cs==0 writes X), -90 launches
//  - ln2(l) folded into k_qkv(l+1) prologue for l=0,1 (cs==0 writes X), -60 launches
//  - ln2(l2) folded into k_proj prologue (no X write needed), -30 launches
//  - k_attn at 512 threads (R3-verified body)
// R5's FATCORE/k_bnd reverted (regression: halved compute waves -> latency exposed).
// 720 -> 540 launches. GEMM cores/accumulation orders identical to R2.

#define Nn 512
#define Dd 130
#define DP 132
#define Hh 128
#define Ee 64
#define FFf 2048
#define KG 192
#define TS 68

typedef float v4 __attribute__((ext_vector_type(4)));
typedef float v2 __attribute__((ext_vector_type(2)));

struct Args {
  const float *Tracks, *W_emb, *b_emb, *W_ih, *W_hh, *b_ih, *b_hh;
  const float *qkv_w, *qkv_b, *out_w, *out_b, *ff1_w, *ff1_b, *ff2_w, *ff2_b;
  const float *ln1_s, *ln1_b, *ln2_s, *ln2_b;
  const float *W_sp, *b_sp, *W_p1, *b_p1, *W_p2, *b_p2, *W_pl, *b_pl;
  float *X, *T, *Q, *Kb, *V, *O, *Sh, *C, *X1, *X2, *Y, *PART, *outp;
};

__device__ __forceinline__ float sigm(float x){ return 1.f/(1.f+__expf(-x)); }

// row-local LN helper pieces (64 rows/block, 512 threads = 64 rows x 8 lanes)
#define LN_REDUCE(SCR) \
  { int row=tid>>3, l8=tid&7; float s1=0.f, s2=0.f; \
    for (int k=0;k<17;k++){ int c=l8+8*k; if(c<Dd){ float v=(SCR)[row*132+c]; s1+=v; s2+=v*v; } } \
    red1[row*9+l8]=s1; red2_[row*9+l8]=s2; } \
  __syncthreads(); \
  if (tid<64){ float s1=0.f,s2=0.f; \
    for (int k=0;k<8;k++){ s1+=red1[tid*9+k]; s2+=red2_[tid*9+k]; } \
    float m=s1/130.f; mu[tid]=m; inv[tid]=rsqrtf(s2/130.f-m*m+1e-5f); } \
  __syncthreads();

// ---------------- proj (+fused ln2 layer2): Sh = ln2(X+f+PART) @ W_sp^T + b_sp. grid 16 ----------
__global__ __launch_bounds__(512) void k_proj(Args a){
  int rg = blockIdx.x & 7, cs = blockIdx.x >> 3;
  int r0 = rg*64, c0 = cs*64;
  __shared__ alignas(16) float xs[Dd*TS];
  __shared__ alignas(16) float ws[Dd*TS];
  __shared__ float red1[64*9], red2_[64*9], mu[64], inv[64];
  int tid = threadIdx.x, cg = tid & 15, ig = tid >> 4;
  const float* f2b = a.ff2_b + 2*Dd;
  const float* lns = a.ln2_s + 2*Dd;
  const float* lnb = a.ln2_b + 2*Dd;
  for (int idx=tid; idx<64*Dd; idx+=512){ int i=idx/Dd, j=idx-i*Dd;
    float sum = a.X[(r0+i)*DP+j] + f2b[j];
    for (int ksl=0;ksl<16;ksl++) sum += a.PART[(ksl*Nn + r0+i)*DP + j];
    ws[i*132+j] = sum; }
  __syncthreads();
  LN_REDUCE(ws)
  for (int idx=tid; idx<64*Dd; idx+=512){ int i=idx/Dd, j=idx-i*Dd;
    xs[j*TS+i] = (ws[i*132+j]-mu[i])*inv[i]*lns[j] + lnb[j]; }
  __syncthreads();
  for (int idx=tid; idx<64*Dd; idx+=512){ int c=idx/Dd, j=idx-c*Dd; ws[j*TS+c] = a.W_sp[(c0+c)*Dd+j]; }
  __syncthreads();
  float acc[2][4] = {};
  const float* xp = xs + 2*ig;
  const float* wp = ws + 4*cg;
  #pragma unroll 4
  for (int j=0;j<Dd;j++){
    v2 xv = *(const v2*)(xp + j*TS);
    v4 wv = *(const v4*)(wp + j*TS);
    #pragma unroll
    for (int aa=0;aa<2;aa++)
      #pragma unroll
      for (int bb=0;bb<4;bb++) acc[aa][bb] += xv[aa]*wv[bb];
  }
  #pragma unroll
  for (int aa=0;aa<2;aa++){
    int r = r0 + 2*ig + aa, c = c0 + 4*cg;
    v4 o;
    #pragma unroll
    for (int bb=0;bb<4;bb++) o[bb] = acc[aa][bb] + a.b_sp[c+bb];
    *(v4*)&a.Sh[r*Hh+c] = o;
  }
}

// ---------------- out = relu(in@W^T+b)+in (512x128, K=128), grid 16 ----------------
__global__ __launch_bounds__(512) void k_mlp(Args a, const float* inp, const float* W, const float* b, float* outp){
  int rg = blockIdx.x & 7, cs = blockIdx.x >> 3;
  int r0 = rg*64, c0 = cs*64;
  __shared__ alignas(16) float xs[Hh*TS];
  __shared__ alignas(16) float ws[Hh*TS];
  int tid = threadIdx.x, cg = tid & 15, ig = tid >> 4;
  for (int idx=tid; idx<64*Hh; idx+=512){ int i=idx>>7, j=idx&127; xs[j*TS+i] = inp[(r0+i)*Hh+j]; }
  for (int idx=tid; idx<64*Hh; idx+=512){ int c=idx>>7, j=idx&127; ws[j*TS+c] = W[(c0+c)*Hh+j]; }
  __syncthreads();
  float acc[2][4] = {};
  const float* xp = xs + 2*ig;
  const float* wp = ws + 4*cg;
  #pragma unroll 4
  for (int j=0;j<Hh;j++){
    v2 xv = *(const v2*)(xp + j*TS);
    v4 wv = *(const v4*)(wp + j*TS);
    #pragma unroll
    for (int aa=0;aa<2;aa++)
      #pragma unroll
      for (int bb=0;bb<4;bb++) acc[aa][bb] += xv[aa]*wv[bb];
  }
  #pragma unroll
  for (int aa=0;aa<2;aa++){
    int r = r0 + 2*ig + aa, c = c0 + 4*cg;
    v4 ri = *(const v4*)&inp[r*Hh+c];
    v4 o;
    #pragma unroll
    for (int bb=0;bb<4;bb++) o[bb] = fmaxf(acc[aa][bb]+b[c+bb],0.f) + ri[bb];
    *(v4*)&outp[r*Hh+c] = o;
  }
}

// ---------------- pred head. grid 64 (8 rows/blk), 256 thr ----------------
__global__ __launch_bounds__(256) void k_pout(Args a, int p){
  int r0 = blockIdx.x*8;
  __shared__ float red[16*17];
  int tid = threadIdx.x;
  int o = tid & 15, kq = tid >> 4;
  int ii = o>>1, jj = o&1, r = r0+ii;
  float s = 0.f;
  for (int v=kq*8; v<kq*8+8; v++) s += a.X2[r*Hh+v]*a.W_pl[jj*Hh+v];
  red[o*17+kq] = s;
  __syncthreads();
  if (tid < 16){
    int oo=tid, i2=oo>>1, j=oo&1, rr=r0+i2;
    float av = a.b_pl[j];
    for (int k=0;k<16;k++) av += red[oo*17+k];
    float cf0, cf2;
    if (p==0){ cf0 = a.Tracks[(rr*20+19)*5+1+j]; cf2 = a.Tracks[(rr*20+19)*5+3+j]; }
    else     { cf0 = a.outp[rr*40+(p-1)*4+j];    cf2 = a.outp[rr*40+(p-1)*4+2+j]; }
    float vv = av*0.1f + cf2;
    float pn = av*0.005f + vv*0.1f + cf0;
    a.outp[rr*40+p*4+j]   = pn;
    a.outp[rr*40+p*4+2+j] = vv;
  }
}

// ---------------- emb + LSTM gates. grid 64 = 8rg x 8us ----------------
__global__ __launch_bounds__(512) void k_gates(Args a, int xin_mode, int tstep, int p, int sh_zero){
  int rg = blockIdx.x & 7, us = blockIdx.x >> 3;
  int r0 = rg*64, u0 = us*16;
  __shared__ alignas(16) float xs[KG*TS];
  __shared__ alignas(16) float ws[KG*TS];
  __shared__ float xin[64*4];
  int tid = threadIdx.x, cg = tid & 15, ig = tid >> 4;
  for (int idx=tid; idx<64*4; idx+=512){ int i=idx>>2, j=idx&3; int r=r0+i;
    xin[i*4+j] = (xin_mode==0) ? a.Tracks[(r*20+tstep)*5+1+j] : a.outp[r*40+p*4+j]; }
  for (int idx=tid; idx<64*Hh; idx+=512){ int i=idx>>7, v=idx&127;
    xs[(Ee+v)*TS+i] = sh_zero ? 0.f : a.Sh[(r0+i)*Hh+v]; }
  for (int idx=tid; idx<64*KG; idx+=512){ int row=idx/KG, j=idx-row*KG;
    int u=row>>2, g=row&3; int wrow = g*Hh + u0 + u;
    ws[j*TS+row] = (j<Ee) ? a.W_ih[wrow*Ee+j] : a.W_hh[wrow*Hh+(j-Ee)]; }
  __syncthreads();
  for (int idx=tid; idx<64*Ee; idx+=512){ int e=idx>>6, i=idx&63;
    float s = a.b_emb[e];
    #pragma unroll
    for (int j=0;j<4;j++) s += xin[i*4+j]*a.W_emb[e*4+j];
    xs[e*TS+i] = s; }
  __syncthreads();
  float acc[2][4] = {};
  const float* xp = xs + 2*ig;
  const float* wp = ws + 4*cg;
  #pragma unroll 4
  for (int j=0;j<KG;j++){
    v2 xv = *(const v2*)(xp + j*TS);
    v4 wv = *(const v4*)(wp + j*TS);
    #pragma unroll
    for (int aa=0;aa<2;aa++)
      #pragma unroll
      for (int bb=0;bb<4;bb++) acc[aa][bb] += xv[aa]*wv[bb];
  }
  int u = u0 + cg;
  #pragma unroll
  for (int rr=0;rr<2;rr++){
    int r = r0 + 2*ig + rr;
    float gi = acc[rr][0] + a.b_ih[u]      + a.b_hh[u];
    float gf = acc[rr][1] + a.b_ih[Hh+u]   + a.b_hh[Hh+u];
    float gg = acc[rr][2] + a.b_ih[2*Hh+u] + a.b_hh[2*Hh+u];
    float go = acc[rr][3] + a.b_ih[3*Hh+u] + a.b_hh[3*Hh+u];
    float cp = sh_zero ? 0.f : a.C[r*Hh+u];
    float c2 = sigm(gf)*cp + sigm(gi)*tanhf(gg);
    a.C[r*Hh+u] = c2;
    a.X[r*DP+u] = sigm(go)*tanhf(c2);
  }
  if (us==0 && tid<128){ int i=tid>>1, jj=tid&1;
    a.X[(r0+i)*DP + Hh + jj] = xin[i*4+jj]; }
}

// ---------------- QKV (+fused ln2 of prev layer when lnprev): grid 56 = 8rg x 7cs ----------------
__global__ __launch_bounds__(512) void k_qkv(Args a, int layer, int lnprev){
  int rg = blockIdx.x & 7, cs = blockIdx.x >> 3;
  int r0 = rg*64, c0 = cs*64;
  __shared__ alignas(16) float xs[Dd*TS];
  __shared__ alignas(16) float ws[Dd*TS];
  __shared__ float red1[64*9], red2_[64*9], mu[64], inv[64];
  const float* qw = a.qkv_w + layer*390*Dd;
  const float* qb = a.qkv_b + layer*390;
  int tid = threadIdx.x, cg = tid & 15, ig = tid >> 4;
  if (lnprev){
    const float* f2b = a.ff2_b + (layer-1)*Dd;
    const float* lns = a.ln2_s + (layer-1)*Dd;
    const float* lnb = a.ln2_b + (layer-1)*Dd;
    for (int idx=tid; idx<64*Dd; idx+=512){ int i=idx/Dd, j=idx-i*Dd;
      float sum = a.X[(r0+i)*DP+j] + f2b[j];
      for (int ksl=0;ksl<16;ksl++) sum += a.PART[(ksl*Nn + r0+i)*DP + j];
      ws[i*132+j] = sum; }
    __syncthreads();
    LN_REDUCE(ws)
    for (int idx=tid; idx<64*Dd; idx+=512){ int i=idx/Dd, j=idx-i*Dd;
      float v = (ws[i*132+j]-mu[i])*inv[i]*lns[j] + lnb[j];
      xs[j*TS+i] = v;
      if (cs==0) a.X[(r0+i)*DP+j] = v; }
    __syncthreads();
  } else {
    for (int idx=tid; idx<64*Dd; idx+=512){ int i=idx/Dd, j=idx-i*Dd; xs[j*TS+i] = a.X[(r0+i)*DP+j]; }
  }
  for (int idx=tid; idx<64*Dd; idx+=512){ int c=idx/Dd, j=idx-c*Dd; int gc=c0+c;
    ws[j*TS+c] = (gc<390) ? qw[gc*Dd+j] : 0.f; }
  __syncthreads();
  float acc[2][4] = {};
  const float* xp = xs + 2*ig;
  const float* wp = ws + 4*cg;
  #pragma unroll 4
  for (int j=0;j<Dd;j++){
    v2 xv = *(const v2*)(xp + j*TS);
    v4 wv = *(const v4*)(wp + j*TS);
    #pragma unroll
    for (int aa=0;aa<2;aa++)
      #pragma unroll
      for (int bb=0;bb<4;bb++) acc[aa][bb] += xv[aa]*wv[bb];
  }
  #pragma unroll
  for (int aa=0;aa<2;aa++){
    int r = r0 + 2*ig + aa;
    #pragma unroll
    for (int bb=0;bb<4;bb++){
      int c = c0 + 4*cg + bb;
      if (c < 390){
        float v = acc[aa][bb] + qb[c];
        if (c < Dd)        a.Q [r*DP + c]        = v;
        else if (c < 2*Dd) a.Kb[r*DP + (c-Dd)]   = v;
        else               a.V [r*DP + (c-2*Dd)] = v;
      }
    }
  }
}

// ---------------- attention: grid 320 (16-row tile x head), 512 thr (R3-verified body) -----------
__global__ __launch_bounds__(512) void k_attn(Args a){
  __shared__ alignas(16) float kv[512*14];   // K [m][14]; then V^T [13][524]
  __shared__ alignas(16) float sc[16*516];
  __shared__ float red[16*33];
  __shared__ float rowm[16], rowsi[16];
  __shared__ float red2[416];
  int rg = blockIdx.x & 31, head = blockIdx.x >> 5;
  int r0 = rg*16, hc = head*13;
  int tid = threadIdx.x;
  const float scale = rsqrtf(13.f);
  for (int idx=tid; idx<512*13; idx+=512){ int m=idx/13, d=idx-13*m; kv[m*14+d]=a.Kb[m*DP+hc+d]; }
  __syncthreads();
  { int ii=tid>>5, mg=tid&31;
    float q[13];
    #pragma unroll
    for (int d=0;d<13;d++) q[d]=a.Q[(r0+ii)*DP+hc+d]*scale;
    for (int k=0;k<16;k++){ int m=mg+32*k;
      float s=0.f;
      #pragma unroll
      for (int d=0;d<13;d++) s += q[d]*kv[m*14+d];
      sc[ii*516+m]=s; } }
  __syncthreads();
  for (int idx=tid; idx<512*13; idx+=512){ int m=idx/13, d=idx-13*m; kv[d*524+m]=a.V[m*DP+hc+d]; }
  { int row=tid>>5, l=tid&31; float mx=-1e30f;
    for (int k=0;k<16;k++) mx=fmaxf(mx, sc[row*516+l+32*k]);
    red[row*33+l]=mx; }
  __syncthreads();
  if (tid<16){ float mx=-1e30f; for(int k=0;k<32;k++) mx=fmaxf(mx,red[tid*33+k]); rowm[tid]=mx; }
  __syncthreads();
  { int row=tid>>5, l=tid&31; float s=0.f; float mx=rowm[row];
    for (int k=0;k<16;k++){ int m=l+32*k; float e=__expf(sc[row*516+m]-mx); sc[row*516+m]=e; s+=e; }
    red[row*33+l]=s; }
  __syncthreads();
  if (tid<16){ float s=0.f; for(int k=0;k<32;k++) s+=red[tid*33+k]; rowsi[tid]=1.f/s; }
  __syncthreads();
  if (tid<416){ int pid=tid>>1, h=tid&1; int ii=pid/13, d=pid-13*ii;
    const float* sp = sc + ii*516 + h*256;
    const float* vp = kv + d*524 + h*256;
    float accv=0.f;
    #pragma unroll 4
    for (int mb=0;mb<64;mb++){
      v4 sv = *(const v4*)(sp + 4*mb);
      v4 vv = *(const v4*)(vp + 4*mb);
      accv += sv[0]*vv[0]+sv[1]*vv[1]+sv[2]*vv[2]+sv[3]*vv[3];
    }
    red2[pid*2+h]=accv; }
  __syncthreads();
  if (tid<208){ int ii=tid/13, d=tid-13*ii;
    a.O[(r0+ii)*DP+hc+d]=(red2[tid*2]+red2[tid*2+1])*rowsi[ii]; }
}

// ---------------- attn out-proj + residual: T = O@ow^T + ob + X. grid 24 = 8rg x 3cs -------------
__global__ __launch_bounds__(512) void k_oproj(Args a, int layer){
  int rg = blockIdx.x & 7, cs = blockIdx.x >> 3;
  int r0 = rg*64, c0 = cs*64;
  __shared__ alignas(16) float xs[Dd*TS];
  __shared__ alignas(16) float ws[Dd*TS];
  const float* ow = a.out_w + layer*Dd*Dd;
  const float* ob = a.out_b + layer*Dd;
  int tid = threadIdx.x, cg = tid & 15, ig = tid >> 4;
  for (int idx=tid; idx<64*Dd; idx+=512){ int i=idx/Dd, j=idx-i*Dd; xs[j*TS+i]=a.O[(r0+i)*DP+j]; }
  for (int idx=tid; idx<64*Dd; idx+=512){ int c=idx/Dd, j=idx-c*Dd; int gc=c0+c;
    ws[j*TS+c] = (gc<Dd) ? ow[gc*Dd+j] : 0.f; }
  __syncthreads();
  float acc[2][4] = {};
  const float* xp = xs + 2*ig;
  const float* wp = ws + 4*cg;
  #pragma unroll 4
  for (int j=0;j<Dd;j++){
    v2 xv = *(const v2*)(xp + j*TS);
    v4 wv = *(const v4*)(wp + j*TS);
    #pragma unroll
    for (int aa=0;aa<2;aa++)
      #pragma unroll
      for (int bb=0;bb<4;bb++) acc[aa][bb] += xv[aa]*wv[bb];
  }
  #pragma unroll
  for (int aa=0;aa<2;aa++){
    int r = r0 + 2*ig + aa;
    #pragma unroll
    for (int bb=0;bb<4;bb++){
      int c = c0 + 4*cg + bb;
      if (c < Dd) a.T[r*DP+c] = acc[aa][bb] + ob[c] + a.X[r*DP+c];
    }
  }
}

// ---------------- FF1 (+fused ln1): Y = relu(ln1(T)@W1^T + b1). grid 256 = 8rg x 32cs -------------
__global__ __launch_bounds__(512) void k_ff1(Args a, int layer){
  int rg = blockIdx.x & 7, cs = blockIdx.x >> 3;
  int r0 = rg*64, c0 = cs*64;
  __shared__ alignas(16) float xs[Dd*TS];
  __shared__ alignas(16) float ws[Dd*TS];
  __shared__ float red1[64*9], red2_[64*9], mu[64], inv[64];
  const float* w1 = a.ff1_w + layer*FFf*Dd;
  const float* b1 = a.ff1_b + layer*FFf;
  const float* lns = a.ln1_s + layer*Dd;
  const float* lnb = a.ln1_b + layer*Dd;
  int tid = threadIdx.x, cg = tid & 15, ig = tid >> 4;
  for (int idx=tid; idx<64*Dd; idx+=512){ int i=idx/Dd, j=idx-i*Dd; ws[i*132+j]=a.T[(r0+i)*DP+j]; }
  __syncthreads();
  LN_REDUCE(ws)
  for (int idx=tid; idx<64*Dd; idx+=512){ int i=idx/Dd, j=idx-i*Dd;
    float v = (ws[i*132+j]-mu[i])*inv[i]*lns[j] + lnb[j];
    xs[j*TS+i] = v;
    if (cs==0) a.X[(r0+i)*DP+j] = v; }
  __syncthreads();
  for (int idx=tid; idx<64*Dd; idx+=512){ int c=idx/Dd, j=idx-c*Dd; ws[j*TS+c]=w1[(c0+c)*Dd+j]; }
  __syncthreads();
  float acc[2][4] = {};
  const float* xp = xs + 2*ig;
  const float* wp = ws + 4*cg;
  #pragma unroll 4
  for (int j=0;j<Dd;j++){
    v2 xv = *(const v2*)(xp + j*TS);
    v4 wv = *(const v4*)(wp + j*TS);
    #pragma unroll
    for (int aa=0;aa<2;aa++)
      #pragma unroll
      for (int bb=0;bb<4;bb++) acc[aa][bb] += xv[aa]*wv[bb];
  }
  #pragma unroll
  for (int aa=0;aa<2;aa++){
    int r = r0 + 2*ig + aa, c = c0 + 4*cg;
    v4 o;
    #pragma unroll
    for (int bb=0;bb<4;bb++) o[bb] = fmaxf(acc[aa][bb]+b1[c+bb],0.f);
    *(v4*)&a.Y[r*FFf+c] = o;
  }
}

// ---------------- FF2 partials: PART[ks] = Y[:,kslice]@W2[:,kslice]^T. grid 384 = 8rg x 3cs x 16ks -
__global__ __launch_bounds__(512) void k_ff2(Args a, int layer){
  int b = blockIdx.x;
  int rg = b & 7; int t = b >> 3; int ks = t/3; int cs = t - ks*3;
  int r0 = rg*64, c0 = cs*64, k0 = ks*128;
  __shared__ alignas(16) float xs[128*TS];
  __shared__ alignas(16) float ws[128*TS];
  const float* w2 = a.ff2_w + layer*Dd*FFf;
  int tid = threadIdx.x, cg = tid & 15, ig = tid >> 4;
  for (int idx=tid; idx<64*128; idx+=512){ int i=idx>>7, j=idx&127; xs[j*TS+i]=a.Y[(r0+i)*FFf+k0+j]; }
  for (int idx=tid; idx<64*128; idx+=512){ int c=idx>>7, j=idx&127; int gc=c0+c;
    ws[j*TS+c] = (gc<Dd) ? w2[gc*FFf+k0+j] : 0.f; }
  __syncthreads();
  float acc[2][4] = {};
  const float* xp = xs + 2*ig;
  const float* wp = ws + 4*cg;
  #pragma unroll 4
  for (int j=0;j<128;j++){
    v2 xv = *(const v2*)(xp + j*TS);
    v4 wv = *(const v4*)(wp + j*TS);
    #pragma unroll
    for (int aa=0;aa<2;aa++)
      #pragma unroll
      for (int bb=0;bb<4;bb++) acc[aa][bb] += xv[aa]*wv[bb];
  }
  #pragma unroll
  for (int aa=0;aa<2;aa++){
    int r = r0 + 2*ig + aa;
    #pragma unroll
    for (int bb=0;bb<4;bb++){
      int c = c0 + 4*cg + bb;
      if (c < Dd) a.PART[(ks*Nn + r)*DP + c] = acc[aa][bb];
    }
  }
}

extern "C" void kernel_launch(void* const* d_in, const int* in_sizes, int n_in,
                              void* d_out, int out_size, void* d_ws, size_t ws_size,
                              hipStream_t stream) {
  (void)in_sizes; (void)n_in; (void)out_size; (void)ws_size;
  Args A;
  const float* const* in = (const float* const*)d_in;
  A.Tracks=in[0]; A.W_emb=in[1]; A.b_emb=in[2]; A.W_ih=in[3]; A.W_hh=in[4]; A.b_ih=in[5]; A.b_hh=in[6];
  A.qkv_w=in[7]; A.qkv_b=in[8]; A.out_w=in[9]; A.out_b=in[10];
  A.ff1_w=in[11]; A.ff1_b=in[12]; A.ff2_w=in[13]; A.ff2_b=in[14];
  A.ln1_s=in[15]; A.ln1_b=in[16]; A.ln2_s=in[17]; A.ln2_b=in[18];
  A.W_sp=in[19]; A.b_sp=in[20]; A.W_p1=in[21]; A.b_p1=in[22]; A.W_p2=in[23]; A.b_p2=in[24];
  A.W_pl=in[25]; A.b_pl=in[26];
  float* ws = (float*)d_ws;
  A.X   = ws;
  A.T   = ws + 67584;
  A.Q   = ws + 135168;
  A.Kb  = ws + 202752;
  A.V   = ws + 270336;
  A.O   = ws + 337920;
  A.Sh  = ws + 405504;
  A.C   = ws + 471040;
  A.X1  = ws + 536576;
  A.X2  = ws + 602112;
  A.Y   = ws + 667648;
  A.PART= ws + 1716224;   // 16 * 512 * 132
  A.outp = (float*)d_out;

  dim3 B5(512), B2(256);
  auto enc = [&](){
    for (int l=0;l<3;l++){
      k_qkv  <<<dim3(56),  B5, 0, stream>>>(A, l, l>0 ? 1 : 0);
      k_attn <<<dim3(320), B5, 0, stream>>>(A);
      k_oproj<<<dim3(24),  B5, 0, stream>>>(A, l);
      k_ff1  <<<dim3(256), B5, 0, stream>>>(A, l);
      k_ff2  <<<dim3(384), B5, 0, stream>>>(A, l);
    }
  };

  // init step: lstm(emb(Tracks[:,0,1:]), 0, 0) -> encoder
  k_gates<<<dim3(64), B5, 0, stream>>>(A, 0, 0, 0, 1);
  enc();
  // 20 history steps
  for (int t=0;t<20;t++){
    k_proj <<<dim3(16), B5, 0, stream>>>(A);
    k_gates<<<dim3(64), B5, 0, stream>>>(A, 0, t, 0, 0);
    enc();
  }
  // 10 prediction steps
  for (int p=0;p<10;p++){
    k_proj<<<dim3(16), B5, 0, stream>>>(A);
    k_mlp <<<dim3(16), B5, 0, stream>>>(A, A.Sh, A.W_p1, A.b_p1, A.X1);
    k_mlp <<<dim3(16), B5, 0, stream>>>(A, A.X1, A.W_p2, A.b_p2, A.X2);
    k_pout<<<dim3(64), B2, 0, stream>>>(A, p);
    if (p < 9){
      k_gates<<<dim3(64), B5, 0, stream>>>(A, 1, 0, p, 0);
      enc();
    }
  }
}